// Round 1
// baseline (2228.302 us; speedup 1.0000x reference)
//
#include <hip/hip_runtime.h>
#include <math.h>

#define SCALE 0.125f   // 64^-0.5

// =====================================================================
// GEMM: C[M,N] = A[M,K] @ B[N,K]^T (+ bias[N] if non-null)
// BM=BN=128, BK=8, 256 threads, 8x8 register tile per thread.
// All M,N multiples of 128; K multiple of 8 (1024 or 768 here).
// =====================================================================
__global__ __launch_bounds__(256) void gemm_abt(
    const float* __restrict__ A, const float* __restrict__ B,
    const float* __restrict__ bias, float* __restrict__ C,
    int M, int N, int K)
{
    __shared__ float As[8][128];
    __shared__ float Bs[8][128];
    const int tid = threadIdx.x;
    const int m0 = blockIdx.y * 128;
    const int n0 = blockIdx.x * 128;
    const int lm = tid >> 1;          // 0..127
    const int lk = (tid & 1) * 4;     // 0 or 4
    const int tx = tid & 15;
    const int ty = tid >> 4;

    float acc[8][8];
#pragma unroll
    for (int i = 0; i < 8; ++i)
#pragma unroll
        for (int j = 0; j < 8; ++j) acc[i][j] = 0.f;

    const float* Arow = A + (size_t)(m0 + lm) * K + lk;
    const float* Brow = B + (size_t)(n0 + lm) * K + lk;

    for (int k0 = 0; k0 < K; k0 += 8) {
        float4 a4 = *(const float4*)(Arow + k0);
        float4 b4 = *(const float4*)(Brow + k0);
        As[lk + 0][lm] = a4.x; As[lk + 1][lm] = a4.y;
        As[lk + 2][lm] = a4.z; As[lk + 3][lm] = a4.w;
        Bs[lk + 0][lm] = b4.x; Bs[lk + 1][lm] = b4.y;
        Bs[lk + 2][lm] = b4.z; Bs[lk + 3][lm] = b4.w;
        __syncthreads();
#pragma unroll
        for (int kk = 0; kk < 8; ++kk) {
            float4 a0 = *(float4*)&As[kk][ty * 8];
            float4 a1 = *(float4*)&As[kk][ty * 8 + 4];
            float4 b0 = *(float4*)&Bs[kk][tx * 8];
            float4 b1 = *(float4*)&Bs[kk][tx * 8 + 4];
            float av[8] = {a0.x, a0.y, a0.z, a0.w, a1.x, a1.y, a1.z, a1.w};
            float bv[8] = {b0.x, b0.y, b0.z, b0.w, b1.x, b1.y, b1.z, b1.w};
#pragma unroll
            for (int i = 0; i < 8; ++i)
#pragma unroll
                for (int j = 0; j < 8; ++j)
                    acc[i][j] += av[i] * bv[j];
        }
        __syncthreads();
    }

#pragma unroll
    for (int i = 0; i < 8; ++i) {
        size_t row = (size_t)(m0 + ty * 8 + i);
#pragma unroll
        for (int j = 0; j < 8; j += 4) {
            int col = n0 + tx * 8 + j;
            float4 o;
            o.x = acc[i][j + 0]; o.y = acc[i][j + 1];
            o.z = acc[i][j + 2]; o.w = acc[i][j + 3];
            if (bias) {
                o.x += bias[col + 0]; o.y += bias[col + 1];
                o.z += bias[col + 2]; o.w += bias[col + 3];
            }
            *(float4*)&C[row * N + col] = o;
        }
    }
}

// =====================================================================
// GEMM: C[M,N] = A[M,K] @ B[K,N]   (used for G = fam @ k_b)
// Same tiling as gemm_abt; only the B-tile load differs.
// =====================================================================
__global__ __launch_bounds__(256) void gemm_ab(
    const float* __restrict__ A, const float* __restrict__ B,
    float* __restrict__ C, int M, int N, int K)
{
    __shared__ float As[8][128];
    __shared__ float Bs[8][128];
    const int tid = threadIdx.x;
    const int m0 = blockIdx.y * 128;
    const int n0 = blockIdx.x * 128;
    const int lm = tid >> 1;          // 0..127
    const int lk = (tid & 1) * 4;     // 0 or 4
    const int lk2 = tid >> 5;         // 0..7
    const int ln = (tid & 31) * 4;    // 0..124
    const int tx = tid & 15;
    const int ty = tid >> 4;

    float acc[8][8];
#pragma unroll
    for (int i = 0; i < 8; ++i)
#pragma unroll
        for (int j = 0; j < 8; ++j) acc[i][j] = 0.f;

    const float* Arow = A + (size_t)(m0 + lm) * K + lk;

    for (int k0 = 0; k0 < K; k0 += 8) {
        float4 a4 = *(const float4*)(Arow + k0);
        float4 b4 = *(const float4*)&B[(size_t)(k0 + lk2) * N + n0 + ln];
        As[lk + 0][lm] = a4.x; As[lk + 1][lm] = a4.y;
        As[lk + 2][lm] = a4.z; As[lk + 3][lm] = a4.w;
        *(float4*)&Bs[lk2][ln] = b4;
        __syncthreads();
#pragma unroll
        for (int kk = 0; kk < 8; ++kk) {
            float4 a0 = *(float4*)&As[kk][ty * 8];
            float4 a1 = *(float4*)&As[kk][ty * 8 + 4];
            float4 b0 = *(float4*)&Bs[kk][tx * 8];
            float4 b1 = *(float4*)&Bs[kk][tx * 8 + 4];
            float av[8] = {a0.x, a0.y, a0.z, a0.w, a1.x, a1.y, a1.z, a1.w};
            float bv[8] = {b0.x, b0.y, b0.z, b0.w, b1.x, b1.y, b1.z, b1.w};
#pragma unroll
            for (int i = 0; i < 8; ++i)
#pragma unroll
                for (int j = 0; j < 8; ++j)
                    acc[i][j] += av[i] * bv[j];
        }
        __syncthreads();
    }

#pragma unroll
    for (int i = 0; i < 8; ++i) {
        size_t row = (size_t)(m0 + ty * 8 + i);
#pragma unroll
        for (int j = 0; j < 8; j += 4) {
            int col = n0 + tx * 8 + j;
            float4 o;
            o.x = acc[i][j + 0]; o.y = acc[i][j + 1];
            o.z = acc[i][j + 2]; o.w = acc[i][j + 3];
            *(float4*)&C[row * N + col] = o;
        }
    }
}

// =====================================================================
// Fused FCA attention. One block = (b,h) x 16 q-rows. 256 threads.
// Thread (r = tid/16, jg = tid%16): owns q-row r; handles 4 columns
// {jg, jg+16, jg+32, jg+48} of each 64-wide column tile, and output
// dims jg*4..jg*4+3 in the PV accumulation.
// Pass 1: rowmax of min(|fw|,1), fw = SCALE * q . G_row
// Pass 2: recompute fw + sim, threshold, e = exp(logit) (no max-sub:
//         logits bounded ~[-52, +2.5]), accumulate sum(e*v), sum(e).
// =====================================================================
__global__ __launch_bounds__(256) void attn_fused(
    const float* __restrict__ Q, const float* __restrict__ Kb,
    const float* __restrict__ Vb, const float* __restrict__ Gb,
    float* __restrict__ AO)
{
    __shared__ float qs[16][68];
    __shared__ float t0[64][68];
    __shared__ float t1[64][68];
    __shared__ float et[16][64];
    __shared__ float red[16][16];

    const int tid = threadIdx.x;
    const int bh = blockIdx.y;
    const int b = bh >> 4, h = bh & 15;
    const int qr0 = blockIdx.x * 16;
    const float* qb = Q  + ((size_t)(b * 2048 + qr0)) * 1024 + h * 64;
    const float* kb = Kb + ((size_t)(b * 1024)) * 1024 + h * 64;
    const float* gb = Gb + ((size_t)(b * 1024)) * 1024 + h * 64;
    const float* vb = Vb + ((size_t)(b * 1024)) * 1024 + h * 64;

    const int r = tid >> 4;
    const int jg = tid & 15;

    // load q tile (16 x 64), one float4 per thread
    {
        int rr = tid >> 4, c4 = tid & 15;
        *(float4*)&qs[rr][c4 * 4] = *(const float4*)&qb[(size_t)rr * 1024 + c4 * 4];
    }

    // ---------------- pass 1: rowmax of clamped |fw| ----------------
    float mx = 0.f;
    for (int jt = 0; jt < 16; ++jt) {
        __syncthreads();
#pragma unroll
        for (int i = 0; i < 4; ++i) {
            int idx = tid + i * 256;
            int row = idx >> 4, c4 = idx & 15;
            *(float4*)&t0[row][c4 * 4] =
                *(const float4*)&gb[(size_t)(jt * 64 + row) * 1024 + c4 * 4];
        }
        __syncthreads();
        float s0 = 0.f, s1 = 0.f, s2 = 0.f, s3 = 0.f;
#pragma unroll
        for (int d4 = 0; d4 < 16; ++d4) {
            float4 q4 = *(float4*)&qs[r][d4 * 4];
            float4 g0 = *(float4*)&t0[jg     ][d4 * 4];
            float4 g1 = *(float4*)&t0[jg + 16][d4 * 4];
            float4 g2 = *(float4*)&t0[jg + 32][d4 * 4];
            float4 g3 = *(float4*)&t0[jg + 48][d4 * 4];
            s0 += q4.x * g0.x + q4.y * g0.y + q4.z * g0.z + q4.w * g0.w;
            s1 += q4.x * g1.x + q4.y * g1.y + q4.z * g1.z + q4.w * g1.w;
            s2 += q4.x * g2.x + q4.y * g2.y + q4.z * g2.z + q4.w * g2.w;
            s3 += q4.x * g3.x + q4.y * g3.y + q4.z * g3.z + q4.w * g3.w;
        }
        mx = fmaxf(mx, fminf(fabsf(s0 * SCALE), 1.f));
        mx = fmaxf(mx, fminf(fabsf(s1 * SCALE), 1.f));
        mx = fmaxf(mx, fminf(fabsf(s2 * SCALE), 1.f));
        mx = fmaxf(mx, fminf(fabsf(s3 * SCALE), 1.f));
    }
    red[r][jg] = mx;
    __syncthreads();
    float rowmax = red[r][0];
#pragma unroll
    for (int i = 1; i < 16; ++i) rowmax = fmaxf(rowmax, red[r][i]);
    const float inv = 1.0f / (rowmax + 1e-6f);

    // ---------------- pass 2: attention ----------------
    float4 acc = make_float4(0.f, 0.f, 0.f, 0.f);
    float dsum = 0.f;
    for (int jt = 0; jt < 16; ++jt) {
        __syncthreads();
#pragma unroll
        for (int i = 0; i < 4; ++i) {
            int idx = tid + i * 256;
            int row = idx >> 4, c4 = idx & 15;
            *(float4*)&t0[row][c4 * 4] =
                *(const float4*)&kb[(size_t)(jt * 64 + row) * 1024 + c4 * 4];
            *(float4*)&t1[row][c4 * 4] =
                *(const float4*)&gb[(size_t)(jt * 64 + row) * 1024 + c4 * 4];
        }
        __syncthreads();
        float s0 = 0.f, s1 = 0.f, s2 = 0.f, s3 = 0.f;
        float f0 = 0.f, f1 = 0.f, f2 = 0.f, f3 = 0.f;
#pragma unroll
        for (int d4 = 0; d4 < 16; ++d4) {
            float4 q4 = *(float4*)&qs[r][d4 * 4];
            float4 k0v = *(float4*)&t0[jg     ][d4 * 4];
            float4 k1v = *(float4*)&t0[jg + 16][d4 * 4];
            float4 k2v = *(float4*)&t0[jg + 32][d4 * 4];
            float4 k3v = *(float4*)&t0[jg + 48][d4 * 4];
            float4 g0 = *(float4*)&t1[jg     ][d4 * 4];
            float4 g1 = *(float4*)&t1[jg + 16][d4 * 4];
            float4 g2 = *(float4*)&t1[jg + 32][d4 * 4];
            float4 g3 = *(float4*)&t1[jg + 48][d4 * 4];
            s0 += q4.x * k0v.x + q4.y * k0v.y + q4.z * k0v.z + q4.w * k0v.w;
            s1 += q4.x * k1v.x + q4.y * k1v.y + q4.z * k1v.z + q4.w * k1v.w;
            s2 += q4.x * k2v.x + q4.y * k2v.y + q4.z * k2v.z + q4.w * k2v.w;
            s3 += q4.x * k3v.x + q4.y * k3v.y + q4.z * k3v.z + q4.w * k3v.w;
            f0 += q4.x * g0.x + q4.y * g0.y + q4.z * g0.z + q4.w * g0.w;
            f1 += q4.x * g1.x + q4.y * g1.y + q4.z * g1.z + q4.w * g1.w;
            f2 += q4.x * g2.x + q4.y * g2.y + q4.z * g2.z + q4.w * g2.w;
            f3 += q4.x * g3.x + q4.y * g3.y + q4.z * g3.z + q4.w * g3.w;
        }
        float e0 = __expf(s0 * SCALE + ((fminf(fabsf(f0 * SCALE), 1.f) * inv > 0.6f) ? 0.f : -50.f));
        float e1 = __expf(s1 * SCALE + ((fminf(fabsf(f1 * SCALE), 1.f) * inv > 0.6f) ? 0.f : -50.f));
        float e2 = __expf(s2 * SCALE + ((fminf(fabsf(f2 * SCALE), 1.f) * inv > 0.6f) ? 0.f : -50.f));
        float e3 = __expf(s3 * SCALE + ((fminf(fabsf(f3 * SCALE), 1.f) * inv > 0.6f) ? 0.f : -50.f));
        et[r][jg     ] = e0;
        et[r][jg + 16] = e1;
        et[r][jg + 32] = e2;
        et[r][jg + 48] = e3;
        dsum += e0 + e1 + e2 + e3;
        __syncthreads();
        // stage V tile over t1
#pragma unroll
        for (int i = 0; i < 4; ++i) {
            int idx = tid + i * 256;
            int row = idx >> 4, c4 = idx & 15;
            *(float4*)&t1[row][c4 * 4] =
                *(const float4*)&vb[(size_t)(jt * 64 + row) * 1024 + c4 * 4];
        }
        __syncthreads();
#pragma unroll
        for (int jj4 = 0; jj4 < 16; ++jj4) {
            float4 e4 = *(float4*)&et[r][jj4 * 4];
            float4 v0 = *(float4*)&t1[jj4 * 4 + 0][jg * 4];
            float4 v1 = *(float4*)&t1[jj4 * 4 + 1][jg * 4];
            float4 v2 = *(float4*)&t1[jj4 * 4 + 2][jg * 4];
            float4 v3 = *(float4*)&t1[jj4 * 4 + 3][jg * 4];
            acc.x += e4.x * v0.x + e4.y * v1.x + e4.z * v2.x + e4.w * v3.x;
            acc.y += e4.x * v0.y + e4.y * v1.y + e4.z * v2.y + e4.w * v3.y;
            acc.z += e4.x * v0.z + e4.y * v1.z + e4.z * v2.z + e4.w * v3.z;
            acc.w += e4.x * v0.w + e4.y * v1.w + e4.z * v2.w + e4.w * v3.w;
        }
    }
    red[r][jg] = dsum;
    __syncthreads();
    float denom = 0.f;
#pragma unroll
    for (int i = 0; i < 16; ++i) denom += red[r][i];
    float invd = 1.0f / denom;
    float4 o = make_float4(acc.x * invd, acc.y * invd, acc.z * invd, acc.w * invd);
    *(float4*)&AO[((size_t)(b * 2048 + qr0 + r)) * 1024 + h * 64 + jg * 4] = o;
}

// =====================================================================
// Orchestration
// =====================================================================
extern "C" void kernel_launch(void* const* d_in, const int* in_sizes, int n_in,
                              void* d_out, int out_size, void* d_ws, size_t ws_size,
                              hipStream_t stream)
{
    const float* x   = (const float*)d_in[0];  // (2, 2048, 1024)
    const float* ctx = (const float*)d_in[1];  // (2, 1024, 768)
    const float* fam = (const float*)d_in[2];  // (1, 1024, 1024)
    const float* Wq  = (const float*)d_in[3];  // (1024, 1024)
    const float* Wk  = (const float*)d_in[4];  // (1024, 768)
    const float* Wv  = (const float*)d_in[5];  // (1024, 768)
    const float* Wo  = (const float*)d_in[6];  // (1024, 1024)
    const float* bo  = (const float*)d_in[7];  // (1024,)
    float* out = (float*)d_out;                // (2, 2048, 1024)

    // workspace: q(16MB) k(8) v(8) G(8) ao(16) = 56 MB
    float* q  = (float*)d_ws;
    float* kk = q  + (size_t)4096 * 1024;
    float* vv = kk + (size_t)2048 * 1024;
    float* G  = vv + (size_t)2048 * 1024;
    float* ao = G  + (size_t)2048 * 1024;

    // projections (fp32, A @ B^T)
    gemm_abt<<<dim3(8, 32), 256, 0, stream>>>(x,   Wq, nullptr, q,  4096, 1024, 1024);
    gemm_abt<<<dim3(8, 16), 256, 0, stream>>>(ctx, Wk, nullptr, kk, 2048, 1024, 768);
    gemm_abt<<<dim3(8, 16), 256, 0, stream>>>(ctx, Wv, nullptr, vv, 2048, 1024, 768);

    // G_b = fam @ k_b  (the algebraic collapse of fw = sim @ fam^T)
    gemm_ab<<<dim3(8, 8), 256, 0, stream>>>(fam, kk, G, 1024, 1024, 1024);
    gemm_ab<<<dim3(8, 8), 256, 0, stream>>>(fam, kk + (size_t)1024 * 1024,
                                            G + (size_t)1024 * 1024, 1024, 1024, 1024);

    // fused FCA attention
    attn_fused<<<dim3(128, 32), 256, 0, stream>>>(q, kk, vv, G, ao);

    // output projection + bias
    gemm_abt<<<dim3(8, 32), 256, 0, stream>>>(ao, Wo, bo, out, 4096, 1024, 1024);
}

// Round 2
// 1431.666 us; speedup vs baseline: 1.5564x; 1.5564x over previous
//
#include <hip/hip_runtime.h>
#include <hip/hip_fp16.h>
#include <math.h>

#define SCALE 0.125f   // 64^-0.5

// =====================================================================
// GEMM: C[M,N] = A[M,K] @ B[N,K]^T (+ bias[N] if non-null)
// BM=BN=128, BK=16, 256 threads, 8x8 register tile per thread.
// Column mapping per thread: tx*4..+3 and 64+tx*4..+3 (2-way LDS only).
// =====================================================================
__global__ __launch_bounds__(256) void gemm_abt(
    const float* __restrict__ A, const float* __restrict__ B,
    const float* __restrict__ bias, float* __restrict__ C,
    int M, int N, int K)
{
    __shared__ float As[16][128];
    __shared__ float Bs[16][128];
    const int tid = threadIdx.x;
    const int m0 = blockIdx.y * 128;
    const int n0 = blockIdx.x * 128;
    const int lm = tid >> 1;          // 0..127
    const int lk = (tid & 1) * 4;     // 0 or 4 (covers k lk..lk+3 and lk+8..lk+11)
    const int tx = tid & 15;
    const int ty = tid >> 4;

    float acc[8][8];
#pragma unroll
    for (int i = 0; i < 8; ++i)
#pragma unroll
        for (int j = 0; j < 8; ++j) acc[i][j] = 0.f;

    const float* Arow = A + (size_t)(m0 + lm) * K + lk;
    const float* Brow = B + (size_t)(n0 + lm) * K + lk;

    for (int k0 = 0; k0 < K; k0 += 16) {
        float4 a4 = *(const float4*)(Arow + k0);
        float4 a4b = *(const float4*)(Arow + k0 + 8);
        float4 b4 = *(const float4*)(Brow + k0);
        float4 b4b = *(const float4*)(Brow + k0 + 8);
        As[lk + 0][lm] = a4.x;  As[lk + 1][lm] = a4.y;
        As[lk + 2][lm] = a4.z;  As[lk + 3][lm] = a4.w;
        As[lk + 8][lm] = a4b.x; As[lk + 9][lm] = a4b.y;
        As[lk +10][lm] = a4b.z; As[lk +11][lm] = a4b.w;
        Bs[lk + 0][lm] = b4.x;  Bs[lk + 1][lm] = b4.y;
        Bs[lk + 2][lm] = b4.z;  Bs[lk + 3][lm] = b4.w;
        Bs[lk + 8][lm] = b4b.x; Bs[lk + 9][lm] = b4b.y;
        Bs[lk +10][lm] = b4b.z; Bs[lk +11][lm] = b4b.w;
        __syncthreads();
#pragma unroll
        for (int kk = 0; kk < 16; ++kk) {
            float4 a0 = *(float4*)&As[kk][ty * 8];
            float4 a1 = *(float4*)&As[kk][ty * 8 + 4];
            float4 b0 = *(float4*)&Bs[kk][tx * 4];
            float4 b1 = *(float4*)&Bs[kk][tx * 4 + 64];
            float av[8] = {a0.x, a0.y, a0.z, a0.w, a1.x, a1.y, a1.z, a1.w};
            float bv[8] = {b0.x, b0.y, b0.z, b0.w, b1.x, b1.y, b1.z, b1.w};
#pragma unroll
            for (int i = 0; i < 8; ++i)
#pragma unroll
                for (int j = 0; j < 8; ++j)
                    acc[i][j] += av[i] * bv[j];
        }
        __syncthreads();
    }

#pragma unroll
    for (int i = 0; i < 8; ++i) {
        size_t row = (size_t)(m0 + ty * 8 + i);
        int col0 = n0 + tx * 4;
        int col1 = n0 + tx * 4 + 64;
        float4 o0, o1;
        o0.x = acc[i][0]; o0.y = acc[i][1]; o0.z = acc[i][2]; o0.w = acc[i][3];
        o1.x = acc[i][4]; o1.y = acc[i][5]; o1.z = acc[i][6]; o1.w = acc[i][7];
        if (bias) {
            o0.x += bias[col0 + 0]; o0.y += bias[col0 + 1];
            o0.z += bias[col0 + 2]; o0.w += bias[col0 + 3];
            o1.x += bias[col1 + 0]; o1.y += bias[col1 + 1];
            o1.z += bias[col1 + 2]; o1.w += bias[col1 + 3];
        }
        *(float4*)&C[row * N + col0] = o0;
        *(float4*)&C[row * N + col1] = o1;
    }
}

// =====================================================================
// GEMM: C[M,N] = A[M,K] @ B[K,N]   (used for G = fam @ k_b)
// =====================================================================
__global__ __launch_bounds__(256) void gemm_ab(
    const float* __restrict__ A, const float* __restrict__ B,
    float* __restrict__ C, int M, int N, int K)
{
    __shared__ float As[16][128];
    __shared__ float Bs[16][128];
    const int tid = threadIdx.x;
    const int m0 = blockIdx.y * 128;
    const int n0 = blockIdx.x * 128;
    const int lm = tid >> 1;          // 0..127
    const int lk = (tid & 1) * 4;     // 0 or 4
    const int lk2 = tid >> 5;         // 0..7 (rows lk2, lk2+8)
    const int ln = (tid & 31) * 4;    // 0..124
    const int tx = tid & 15;
    const int ty = tid >> 4;

    float acc[8][8];
#pragma unroll
    for (int i = 0; i < 8; ++i)
#pragma unroll
        for (int j = 0; j < 8; ++j) acc[i][j] = 0.f;

    const float* Arow = A + (size_t)(m0 + lm) * K + lk;

    for (int k0 = 0; k0 < K; k0 += 16) {
        float4 a4 = *(const float4*)(Arow + k0);
        float4 a4b = *(const float4*)(Arow + k0 + 8);
        float4 b4 = *(const float4*)&B[(size_t)(k0 + lk2) * N + n0 + ln];
        float4 b4b = *(const float4*)&B[(size_t)(k0 + lk2 + 8) * N + n0 + ln];
        As[lk + 0][lm] = a4.x;  As[lk + 1][lm] = a4.y;
        As[lk + 2][lm] = a4.z;  As[lk + 3][lm] = a4.w;
        As[lk + 8][lm] = a4b.x; As[lk + 9][lm] = a4b.y;
        As[lk +10][lm] = a4b.z; As[lk +11][lm] = a4b.w;
        *(float4*)&Bs[lk2][ln] = b4;
        *(float4*)&Bs[lk2 + 8][ln] = b4b;
        __syncthreads();
#pragma unroll
        for (int kk = 0; kk < 16; ++kk) {
            float4 a0 = *(float4*)&As[kk][ty * 8];
            float4 a1 = *(float4*)&As[kk][ty * 8 + 4];
            float4 b0 = *(float4*)&Bs[kk][tx * 4];
            float4 b1 = *(float4*)&Bs[kk][tx * 4 + 64];
            float av[8] = {a0.x, a0.y, a0.z, a0.w, a1.x, a1.y, a1.z, a1.w};
            float bv[8] = {b0.x, b0.y, b0.z, b0.w, b1.x, b1.y, b1.z, b1.w};
#pragma unroll
            for (int i = 0; i < 8; ++i)
#pragma unroll
                for (int j = 0; j < 8; ++j)
                    acc[i][j] += av[i] * bv[j];
        }
        __syncthreads();
    }

#pragma unroll
    for (int i = 0; i < 8; ++i) {
        size_t row = (size_t)(m0 + ty * 8 + i);
        int col0 = n0 + tx * 4;
        int col1 = n0 + tx * 4 + 64;
        float4 o0, o1;
        o0.x = acc[i][0]; o0.y = acc[i][1]; o0.z = acc[i][2]; o0.w = acc[i][3];
        o1.x = acc[i][4]; o1.y = acc[i][5]; o1.z = acc[i][6]; o1.w = acc[i][7];
        *(float4*)&C[row * N + col0] = o0;
        *(float4*)&C[row * N + col1] = o1;
    }
}

// =====================================================================
// Fused FCA attention, register-tiled.
// Block = 64 q-rows of one (b,h); 256 threads; j-tiles of 64 columns.
// Thread (qg=tid>>4, cg=tid&15): 4x4 tile of sim AND fw; 4q x 4dim of O.
// Pass 1: rowmax of min(|fw*SCALE|,1)  (fw = q . G^T)
// Pass 2: sim+fw recompute -> threshold -> exp -> P (fp16 via LDS) -> PV.
// fw-critical math is bit-identical fp32 to round 1 (passed, 6.1e-4).
// =====================================================================
__global__ __launch_bounds__(256) void attn_fused(
    const float* __restrict__ Q, const float* __restrict__ Kb,
    const float* __restrict__ Vb, const float* __restrict__ Gb,
    float* __restrict__ AO)
{
    __shared__ float qs[64][68];     // 17408 B
    __shared__ float ks[64][68];     // 17408 B
    __shared__ float gs[64][68];     // 17408 B (G, then reused for V)
    __shared__ __half Ps[64][68];    //  8704 B  P[c][q] col-major
    __shared__ float red[64][16];    //  4096 B  -> total 65024 B

    const int tid = threadIdx.x;
    const int bh = blockIdx.y;
    const int b = bh >> 4, h = bh & 15;
    const int qr0 = blockIdx.x * 64;
    const float* qp = Q  + ((size_t)(b * 2048 + qr0)) * 1024 + h * 64;
    const float* kp = Kb + ((size_t)(b * 1024)) * 1024 + h * 64;
    const float* gp = Gb + ((size_t)(b * 1024)) * 1024 + h * 64;
    const float* vp = Vb + ((size_t)(b * 1024)) * 1024 + h * 64;

    const int qg = tid >> 4;   // 0..15
    const int cg = tid & 15;   // 0..15

    // stage q tile (64 x 64): 4 float4 per thread
#pragma unroll
    for (int i = 0; i < 4; ++i) {
        int idx = tid + i * 256;
        int row = idx >> 4, c4 = idx & 15;
        *(float4*)&qs[row][c4 * 4] = *(const float4*)&qp[(size_t)row * 1024 + c4 * 4];
    }

    // ---------------- pass 1: rowmax of min(|fw|,1) ----------------
    float mx[4] = {0.f, 0.f, 0.f, 0.f};
    for (int jt = 0; jt < 16; ++jt) {
        __syncthreads();
#pragma unroll
        for (int i = 0; i < 4; ++i) {
            int idx = tid + i * 256;
            int row = idx >> 4, c4 = idx & 15;
            *(float4*)&gs[row][c4 * 4] =
                *(const float4*)&gp[(size_t)(jt * 64 + row) * 1024 + c4 * 4];
        }
        __syncthreads();
        float fw[4][4] = {};
#pragma unroll 4
        for (int d4 = 0; d4 < 16; ++d4) {
            float4 qv[4], gv[4];
#pragma unroll
            for (int i = 0; i < 4; ++i) qv[i] = *(float4*)&qs[qg * 4 + i][d4 * 4];
#pragma unroll
            for (int j = 0; j < 4; ++j) gv[j] = *(float4*)&gs[cg * 4 + j][d4 * 4];
#pragma unroll
            for (int i = 0; i < 4; ++i)
#pragma unroll
                for (int j = 0; j < 4; ++j)
                    fw[i][j] += qv[i].x * gv[j].x + qv[i].y * gv[j].y
                              + qv[i].z * gv[j].z + qv[i].w * gv[j].w;
        }
#pragma unroll
        for (int i = 0; i < 4; ++i)
#pragma unroll
            for (int j = 0; j < 4; ++j)
                mx[i] = fmaxf(mx[i], fminf(fabsf(fw[i][j] * SCALE), 1.f));
    }
    __syncthreads();
#pragma unroll
    for (int i = 0; i < 4; ++i) red[qg * 4 + i][cg] = mx[i];
    __syncthreads();
    float inv[4];
#pragma unroll
    for (int i = 0; i < 4; ++i) {
        float m = 0.f;
#pragma unroll
        for (int c = 0; c < 16; ++c) m = fmaxf(m, red[qg * 4 + i][c]);
        inv[i] = 1.0f / (m + 1e-6f);
    }

    // ---------------- pass 2: attention ----------------
    float4 Ov[4];
#pragma unroll
    for (int i = 0; i < 4; ++i) Ov[i] = make_float4(0.f, 0.f, 0.f, 0.f);
    float dsum[4] = {0.f, 0.f, 0.f, 0.f};

    for (int jt = 0; jt < 16; ++jt) {
        __syncthreads();
#pragma unroll
        for (int i = 0; i < 4; ++i) {
            int idx = tid + i * 256;
            int row = idx >> 4, c4 = idx & 15;
            *(float4*)&ks[row][c4 * 4] =
                *(const float4*)&kp[(size_t)(jt * 64 + row) * 1024 + c4 * 4];
            *(float4*)&gs[row][c4 * 4] =
                *(const float4*)&gp[(size_t)(jt * 64 + row) * 1024 + c4 * 4];
        }
        __syncthreads();
        float sv[4][4] = {};
        float fv[4][4] = {};
#pragma unroll 4
        for (int d4 = 0; d4 < 16; ++d4) {
            float4 qv[4], kv[4], gv[4];
#pragma unroll
            for (int i = 0; i < 4; ++i) qv[i] = *(float4*)&qs[qg * 4 + i][d4 * 4];
#pragma unroll
            for (int j = 0; j < 4; ++j) kv[j] = *(float4*)&ks[cg * 4 + j][d4 * 4];
#pragma unroll
            for (int j = 0; j < 4; ++j) gv[j] = *(float4*)&gs[cg * 4 + j][d4 * 4];
#pragma unroll
            for (int i = 0; i < 4; ++i)
#pragma unroll
                for (int j = 0; j < 4; ++j) {
                    sv[i][j] += qv[i].x * kv[j].x + qv[i].y * kv[j].y
                              + qv[i].z * kv[j].z + qv[i].w * kv[j].w;
                    fv[i][j] += qv[i].x * gv[j].x + qv[i].y * gv[j].y
                              + qv[i].z * gv[j].z + qv[i].w * gv[j].w;
                }
        }
        float e[4][4];
#pragma unroll
        for (int i = 0; i < 4; ++i) {
#pragma unroll
            for (int j = 0; j < 4; ++j) {
                float pen = (fminf(fabsf(fv[i][j] * SCALE), 1.f) * inv[i] > 0.6f) ? 0.f : -50.f;
                e[i][j] = __expf(sv[i][j] * SCALE + pen);
                dsum[i] += e[i][j];
            }
        }
        __syncthreads();   // d-loop reads of gs done; Ps from prev jt consumed
        // store P col-major (fp16): Ps[c][q]
#pragma unroll
        for (int j = 0; j < 4; ++j) {
            *(__half2*)&Ps[cg * 4 + j][qg * 4]     = __floats2half2_rn(e[0][j], e[1][j]);
            *(__half2*)&Ps[cg * 4 + j][qg * 4 + 2] = __floats2half2_rn(e[2][j], e[3][j]);
        }
        // stage V over gs
#pragma unroll
        for (int i = 0; i < 4; ++i) {
            int idx = tid + i * 256;
            int row = idx >> 4, c4 = idx & 15;
            *(float4*)&gs[row][c4 * 4] =
                *(const float4*)&vp[(size_t)(jt * 64 + row) * 1024 + c4 * 4];
        }
        __syncthreads();
        // PV: O[q][dim] += P[q][c] * V[c][dim]
#pragma unroll 4
        for (int c = 0; c < 64; ++c) {
            __half2 pa = *(const __half2*)&Ps[c][qg * 4];
            __half2 pb = *(const __half2*)&Ps[c][qg * 4 + 2];
            float2 fa = __half22float2(pa);
            float2 fb = __half22float2(pb);
            float4 v4 = *(const float4*)&gs[c][cg * 4];
            Ov[0].x += fa.x * v4.x; Ov[0].y += fa.x * v4.y; Ov[0].z += fa.x * v4.z; Ov[0].w += fa.x * v4.w;
            Ov[1].x += fa.y * v4.x; Ov[1].y += fa.y * v4.y; Ov[1].z += fa.y * v4.z; Ov[1].w += fa.y * v4.w;
            Ov[2].x += fb.x * v4.x; Ov[2].y += fb.x * v4.y; Ov[2].z += fb.x * v4.z; Ov[2].w += fb.x * v4.w;
            Ov[3].x += fb.y * v4.x; Ov[3].y += fb.y * v4.y; Ov[3].z += fb.y * v4.z; Ov[3].w += fb.y * v4.w;
        }
    }

    // denom reduce + write
    __syncthreads();
#pragma unroll
    for (int i = 0; i < 4; ++i) red[qg * 4 + i][cg] = dsum[i];
    __syncthreads();
#pragma unroll
    for (int i = 0; i < 4; ++i) {
        float denom = 0.f;
#pragma unroll
        for (int c = 0; c < 16; ++c) denom += red[qg * 4 + i][c];
        float invd = 1.0f / denom;
        float4 o = make_float4(Ov[i].x * invd, Ov[i].y * invd,
                               Ov[i].z * invd, Ov[i].w * invd);
        *(float4*)&AO[((size_t)(b * 2048 + qr0 + qg * 4 + i)) * 1024 + h * 64 + cg * 4] = o;
    }
}

// =====================================================================
// Orchestration
// =====================================================================
extern "C" void kernel_launch(void* const* d_in, const int* in_sizes, int n_in,
                              void* d_out, int out_size, void* d_ws, size_t ws_size,
                              hipStream_t stream)
{
    const float* x   = (const float*)d_in[0];  // (2, 2048, 1024)
    const float* ctx = (const float*)d_in[1];  // (2, 1024, 768)
    const float* fam = (const float*)d_in[2];  // (1, 1024, 1024)
    const float* Wq  = (const float*)d_in[3];  // (1024, 1024)
    const float* Wk  = (const float*)d_in[4];  // (1024, 768)
    const float* Wv  = (const float*)d_in[5];  // (1024, 768)
    const float* Wo  = (const float*)d_in[6];  // (1024, 1024)
    const float* bo  = (const float*)d_in[7];  // (1024,)
    float* out = (float*)d_out;                // (2, 2048, 1024)

    float* q  = (float*)d_ws;
    float* kk = q  + (size_t)4096 * 1024;
    float* vv = kk + (size_t)2048 * 1024;
    float* G  = vv + (size_t)2048 * 1024;
    float* ao = G  + (size_t)2048 * 1024;

    gemm_abt<<<dim3(8, 32), 256, 0, stream>>>(x,   Wq, nullptr, q,  4096, 1024, 1024);
    gemm_abt<<<dim3(8, 16), 256, 0, stream>>>(ctx, Wk, nullptr, kk, 2048, 1024, 768);
    gemm_abt<<<dim3(8, 16), 256, 0, stream>>>(ctx, Wv, nullptr, vv, 2048, 1024, 768);

    gemm_ab<<<dim3(8, 8), 256, 0, stream>>>(fam, kk, G, 1024, 1024, 1024);
    gemm_ab<<<dim3(8, 8), 256, 0, stream>>>(fam, kk + (size_t)1024 * 1024,
                                            G + (size_t)1024 * 1024, 1024, 1024, 1024);

    attn_fused<<<dim3(32, 32), 256, 0, stream>>>(q, kk, vv, G, ao);

    gemm_abt<<<dim3(8, 32), 256, 0, stream>>>(ao, Wo, bo, out, 4096, 1024, 1024);
}

// Round 3
// 1044.726 us; speedup vs baseline: 2.1329x; 1.3704x over previous
//
#include <hip/hip_runtime.h>
#include <hip/hip_fp16.h>
#include <hip/hip_bf16.h>
#include <math.h>

#define SCALE 0.125f   // 64^-0.5

typedef __attribute__((ext_vector_type(8))) short bf16x8;
typedef __attribute__((ext_vector_type(4))) float f32x4;

// ---------------------------------------------------------------------
// split3: fp32 -> 3 bf16 planes (hi, mid, lo).  a ~= hi + mid + lo to
// ~24 mantissa bits (fp32-grade when recombined via 6 MFMA products).
// Vectorized by 4. n must be a multiple of 4 (all our sizes are).
// ---------------------------------------------------------------------
__device__ __forceinline__ unsigned short bf_bits(float x) {
    __hip_bfloat16 h = __float2bfloat16(x);
    union { __hip_bfloat16 b; unsigned short u; } u;
    u.b = h;
    return u.u;
}
__device__ __forceinline__ float bf_val(float x, unsigned short* bits) {
    __hip_bfloat16 h = __float2bfloat16(x);
    union { __hip_bfloat16 b; unsigned short u; } u;
    u.b = h;
    *bits = u.u;
    return __bfloat162float(h);
}

__global__ __launch_bounds__(256) void split3(
    const float* __restrict__ src, unsigned short* __restrict__ dst, size_t n)
{
    size_t i4 = ((size_t)blockIdx.x * 256 + threadIdx.x) * 4;
    size_t stride = (size_t)gridDim.x * 256 * 4;
    for (; i4 < n; i4 += stride) {
        float4 a = *(const float4*)&src[i4];
        float av[4] = {a.x, a.y, a.z, a.w};
        unsigned short hb[4], mb[4], lb[4];
#pragma unroll
        for (int j = 0; j < 4; ++j) {
            float fh = bf_val(av[j], &hb[j]);
            float r  = av[j] - fh;
            float fm = bf_val(r, &mb[j]);
            float r2 = r - fm;
            lb[j] = bf_bits(r2);
        }
        *(short4*)&dst[i4]         = make_short4(hb[0], hb[1], hb[2], hb[3]);
        *(short4*)&dst[i4 + n]     = make_short4(mb[0], mb[1], mb[2], mb[3]);
        *(short4*)&dst[i4 + 2*n]   = make_short4(lb[0], lb[1], lb[2], lb[3]);
    }
}

// ---------------------------------------------------------------------
// splitT3: transpose + split for k: src fp32 [2][1024][1024] (j,n) ->
// dst bf16 planes [3][2][1024][1024] laid out (n,j).  plane = 2*1024*1024.
// ---------------------------------------------------------------------
__global__ __launch_bounds__(256) void splitT3(
    const float* __restrict__ src, unsigned short* __restrict__ dst, size_t plane)
{
    __shared__ float t[32][33];
    const int b  = blockIdx.z;
    const int j0 = blockIdx.y * 32;
    const int n0 = blockIdx.x * 32;
    const int tx = threadIdx.x & 31;
    const int ty = threadIdx.x >> 5;   // 0..7
    const float* s = src + (size_t)b * 1024 * 1024;
#pragma unroll
    for (int i = 0; i < 4; ++i)
        t[ty + 8*i][tx] = s[(size_t)(j0 + ty + 8*i) * 1024 + n0 + tx];
    __syncthreads();
#pragma unroll
    for (int i = 0; i < 4; ++i) {
        float a = t[tx][ty + 8*i];
        unsigned short hb, mb, lb;
        float fh = bf_val(a, &hb);
        float r  = a - fh;
        float fm = bf_val(r, &mb);
        lb = bf_bits(r - fm);
        size_t o = (size_t)b * 1024 * 1024 + (size_t)(n0 + ty + 8*i) * 1024 + j0 + tx;
        dst[o]             = hb;
        dst[o + plane]     = mb;
        dst[o + 2 * plane] = lb;
    }
}

// ---------------------------------------------------------------------
// gemm_bt3: C[M,N] = A @ B^T (+bias), fp32-grade via bf16x3 splits.
// A planes: [3][M][K] bf16 (stride Aplane elems); B planes: [3][N][K].
// 6 MFMA products: hh, hm, hl, mh, mm, lh  (drops O(2^-24) terms).
// Block 256 thr = 4 waves (2x2 of 64x64), tile 128x128, BK=32.
// mfma_f32_16x16x32_bf16: A frag lane L: m=L&15, k=(L>>4)*8+j;
// C/D: row(m)=(L>>4)*4+reg, col(n)=L&15   [m89/m91-verified layout].
// ---------------------------------------------------------------------
__global__ __launch_bounds__(256) void gemm_bt3(
    const unsigned short* __restrict__ A, size_t Aplane,
    const unsigned short* __restrict__ B, size_t Bplane,
    const float* __restrict__ bias, float* __restrict__ C,
    int M, int N, int K)
{
    __shared__ __align__(16) unsigned short Ash[3][128 * 32];
    __shared__ __align__(16) unsigned short Bsh[3][128 * 32];

    const int tid  = threadIdx.x;
    const int m0   = blockIdx.y * 128;
    const int n0   = blockIdx.x * 128;
    const int w    = tid >> 6;
    const int lane = tid & 63;
    const int wm   = (w >> 1) * 64;
    const int wn   = (w & 1) * 64;
    const int lq   = lane >> 4;    // 0..3
    const int l15  = lane & 15;

    const int srow = tid >> 2;         // 0..63
    const int sc8  = (tid & 3) * 8;    // bf16 col offset (16B granules)

    f32x4 acc[4][4];
#pragma unroll
    for (int mi = 0; mi < 4; ++mi)
#pragma unroll
        for (int ni = 0; ni < 4; ++ni) {
            acc[mi][ni].x = 0.f; acc[mi][ni].y = 0.f;
            acc[mi][ni].z = 0.f; acc[mi][ni].w = 0.f;
        }

    for (int k0 = 0; k0 < K; k0 += 32) {
        __syncthreads();
#pragma unroll
        for (int p = 0; p < 3; ++p) {
            const unsigned short* Ap = A + (size_t)p * Aplane;
            const unsigned short* Bp = B + (size_t)p * Bplane;
            *(float4*)&Ash[p][srow * 32 + sc8] =
                *(const float4*)&Ap[(size_t)(m0 + srow) * K + k0 + sc8];
            *(float4*)&Ash[p][(srow + 64) * 32 + sc8] =
                *(const float4*)&Ap[(size_t)(m0 + srow + 64) * K + k0 + sc8];
            *(float4*)&Bsh[p][srow * 32 + sc8] =
                *(const float4*)&Bp[(size_t)(n0 + srow) * K + k0 + sc8];
            *(float4*)&Bsh[p][(srow + 64) * 32 + sc8] =
                *(const float4*)&Bp[(size_t)(n0 + srow + 64) * K + k0 + sc8];
        }
        __syncthreads();

#pragma unroll
        for (int ap = 0; ap < 3; ++ap) {
            bf16x8 af[4];
#pragma unroll
            for (int mi = 0; mi < 4; ++mi)
                af[mi] = *(const bf16x8*)&Ash[ap][(wm + mi * 16 + l15) * 32 + lq * 8];
#pragma unroll
            for (int bp = 0; bp < 3 - ap; ++bp) {
                bf16x8 bfr[4];
#pragma unroll
                for (int ni = 0; ni < 4; ++ni)
                    bfr[ni] = *(const bf16x8*)&Bsh[bp][(wn + ni * 16 + l15) * 32 + lq * 8];
#pragma unroll
                for (int mi = 0; mi < 4; ++mi)
#pragma unroll
                    for (int ni = 0; ni < 4; ++ni)
                        acc[mi][ni] = __builtin_amdgcn_mfma_f32_16x16x32_bf16(
                            af[mi], bfr[ni], acc[mi][ni], 0, 0, 0);
            }
        }
    }

#pragma unroll
    for (int mi = 0; mi < 4; ++mi) {
#pragma unroll
        for (int ni = 0; ni < 4; ++ni) {
            int row = m0 + wm + mi * 16 + lq * 4;
            int col = n0 + wn + ni * 16 + l15;
            float bb = bias ? bias[col] : 0.f;
            C[(size_t)(row + 0) * N + col] = acc[mi][ni].x + bb;
            C[(size_t)(row + 1) * N + col] = acc[mi][ni].y + bb;
            C[(size_t)(row + 2) * N + col] = acc[mi][ni].z + bb;
            C[(size_t)(row + 3) * N + col] = acc[mi][ni].w + bb;
        }
    }
}

// ---------------------------------------------------------------------
// Fused FCA attention (fp32 math identical to round 1/2), with
// XOR-swizzled LDS: physical float4-column = c4 ^ ((row>>2)&7) on
// unpadded 64-float rows -> K/G fragment reads drop from 8-way to
// 2-way (free) bank aliasing.
// ---------------------------------------------------------------------
#define SW(row, c4) (((row) << 6) + ((((c4) ^ (((row) >> 2) & 7))) << 2))

__global__ __launch_bounds__(256) void attn_fused(
    const float* __restrict__ Q, const float* __restrict__ Kb,
    const float* __restrict__ Vb, const float* __restrict__ Gb,
    float* __restrict__ AO)
{
    __shared__ __align__(16) float qs[64 * 64];
    __shared__ __align__(16) float ks[64 * 64];
    __shared__ __align__(16) float gs[64 * 64];
    __shared__ __align__(16) __half Ps[64][68];
    __shared__ float red[64][16];

    const int tid = threadIdx.x;
    const int bh = blockIdx.y;
    const int b = bh >> 4, h = bh & 15;
    const int qr0 = blockIdx.x * 64;
    const float* qp = Q  + ((size_t)(b * 2048 + qr0)) * 1024 + h * 64;
    const float* kp = Kb + ((size_t)(b * 1024)) * 1024 + h * 64;
    const float* gp = Gb + ((size_t)(b * 1024)) * 1024 + h * 64;
    const float* vp = Vb + ((size_t)(b * 1024)) * 1024 + h * 64;

    const int qg = tid >> 4;   // 0..15
    const int cg = tid & 15;   // 0..15
    const int selq = qg & 7;   // swizzle sel for q rows qg*4+i
    const int selc = cg & 7;   // swizzle sel for k/g rows cg*4+j

    // stage q tile (64x64)
#pragma unroll
    for (int i = 0; i < 4; ++i) {
        int idx = tid + i * 256;
        int row = idx >> 4, c4 = idx & 15;
        *(float4*)&qs[SW(row, c4)] = *(const float4*)&qp[(size_t)row * 1024 + c4 * 4];
    }

    // ---------------- pass 1: rowmax of min(|fw|,1) ----------------
    float mx[4] = {0.f, 0.f, 0.f, 0.f};
    for (int jt = 0; jt < 16; ++jt) {
        __syncthreads();
#pragma unroll
        for (int i = 0; i < 4; ++i) {
            int idx = tid + i * 256;
            int row = idx >> 4, c4 = idx & 15;
            *(float4*)&gs[SW(row, c4)] =
                *(const float4*)&gp[(size_t)(jt * 64 + row) * 1024 + c4 * 4];
        }
        __syncthreads();
        float fw[4][4] = {};
#pragma unroll 4
        for (int d4 = 0; d4 < 16; ++d4) {
            float4 qv[4], gv[4];
#pragma unroll
            for (int i = 0; i < 4; ++i)
                qv[i] = *(float4*)&qs[((qg * 4 + i) << 6) + ((d4 ^ selq) << 2)];
#pragma unroll
            for (int j = 0; j < 4; ++j)
                gv[j] = *(float4*)&gs[((cg * 4 + j) << 6) + ((d4 ^ selc) << 2)];
#pragma unroll
            for (int i = 0; i < 4; ++i)
#pragma unroll
                for (int j = 0; j < 4; ++j)
                    fw[i][j] += qv[i].x * gv[j].x + qv[i].y * gv[j].y
                              + qv[i].z * gv[j].z + qv[i].w * gv[j].w;
        }
#pragma unroll
        for (int i = 0; i < 4; ++i)
#pragma unroll
            for (int j = 0; j < 4; ++j)
                mx[i] = fmaxf(mx[i], fminf(fabsf(fw[i][j] * SCALE), 1.f));
    }
    __syncthreads();
#pragma unroll
    for (int i = 0; i < 4; ++i) red[qg * 4 + i][cg] = mx[i];
    __syncthreads();
    float inv[4];
#pragma unroll
    for (int i = 0; i < 4; ++i) {
        float m = 0.f;
#pragma unroll
        for (int c = 0; c < 16; ++c) m = fmaxf(m, red[qg * 4 + i][c]);
        inv[i] = 1.0f / (m + 1e-6f);
    }

    // ---------------- pass 2: attention ----------------
    float4 Ov[4];
#pragma unroll
    for (int i = 0; i < 4; ++i) Ov[i] = make_float4(0.f, 0.f, 0.f, 0.f);
    float dsum[4] = {0.f, 0.f, 0.f, 0.f};

    for (int jt = 0; jt < 16; ++jt) {
        __syncthreads();
#pragma unroll
        for (int i = 0; i < 4; ++i) {
            int idx = tid + i * 256;
            int row = idx >> 4, c4 = idx & 15;
            *(float4*)&ks[SW(row, c4)] =
                *(const float4*)&kp[(size_t)(jt * 64 + row) * 1024 + c4 * 4];
            *(float4*)&gs[SW(row, c4)] =
                *(const float4*)&gp[(size_t)(jt * 64 + row) * 1024 + c4 * 4];
        }
        __syncthreads();
        float sv[4][4] = {};
        float fv[4][4] = {};
#pragma unroll 4
        for (int d4 = 0; d4 < 16; ++d4) {
            float4 qv[4], kv[4], gv[4];
#pragma unroll
            for (int i = 0; i < 4; ++i)
                qv[i] = *(float4*)&qs[((qg * 4 + i) << 6) + ((d4 ^ selq) << 2)];
#pragma unroll
            for (int j = 0; j < 4; ++j)
                kv[j] = *(float4*)&ks[((cg * 4 + j) << 6) + ((d4 ^ selc) << 2)];
#pragma unroll
            for (int j = 0; j < 4; ++j)
                gv[j] = *(float4*)&gs[((cg * 4 + j) << 6) + ((d4 ^ selc) << 2)];
#pragma unroll
            for (int i = 0; i < 4; ++i)
#pragma unroll
                for (int j = 0; j < 4; ++j) {
                    sv[i][j] += qv[i].x * kv[j].x + qv[i].y * kv[j].y
                              + qv[i].z * kv[j].z + qv[i].w * kv[j].w;
                    fv[i][j] += qv[i].x * gv[j].x + qv[i].y * gv[j].y
                              + qv[i].z * gv[j].z + qv[i].w * gv[j].w;
                }
        }
        float e[4][4];
#pragma unroll
        for (int i = 0; i < 4; ++i) {
#pragma unroll
            for (int j = 0; j < 4; ++j) {
                float pen = (fminf(fabsf(fv[i][j] * SCALE), 1.f) * inv[i] > 0.6f) ? 0.f : -50.f;
                e[i][j] = __expf(sv[i][j] * SCALE + pen);
                dsum[i] += e[i][j];
            }
        }
        __syncthreads();   // sim/fw reads of ks/gs done; prev PV consumed Ps
        // store P col-major fp16: Ps[c][q], one 8B write per j
#pragma unroll
        for (int j = 0; j < 4; ++j) {
            union { __half hx[4]; float2 f2; } u;
            u.hx[0] = __float2half_rn(e[0][j]);
            u.hx[1] = __float2half_rn(e[1][j]);
            u.hx[2] = __float2half_rn(e[2][j]);
            u.hx[3] = __float2half_rn(e[3][j]);
            *(float2*)&Ps[cg * 4 + j][qg * 4] = u.f2;
        }
        // stage V over gs
#pragma unroll
        for (int i = 0; i < 4; ++i) {
            int idx = tid + i * 256;
            int row = idx >> 4, c4 = idx & 15;
            *(float4*)&gs[SW(row, c4)] =
                *(const float4*)&vp[(size_t)(jt * 64 + row) * 1024 + c4 * 4];
        }
        __syncthreads();
        // PV: O[q][dim] += P[q][c] * V[c][dim]
#pragma unroll 4
        for (int c = 0; c < 64; ++c) {
            __half2 pa = *(const __half2*)&Ps[c][qg * 4];
            __half2 pb = *(const __half2*)&Ps[c][qg * 4 + 2];
            float2 fa = __half22float2(pa);
            float2 fb = __half22float2(pb);
            float4 v4 = *(const float4*)&gs[(c << 6) + ((cg ^ ((c >> 2) & 7)) << 2)];
            Ov[0].x += fa.x * v4.x; Ov[0].y += fa.x * v4.y; Ov[0].z += fa.x * v4.z; Ov[0].w += fa.x * v4.w;
            Ov[1].x += fa.y * v4.x; Ov[1].y += fa.y * v4.y; Ov[1].z += fa.y * v4.z; Ov[1].w += fa.y * v4.w;
            Ov[2].x += fb.x * v4.x; Ov[2].y += fb.x * v4.y; Ov[2].z += fb.x * v4.z; Ov[2].w += fb.x * v4.w;
            Ov[3].x += fb.y * v4.x; Ov[3].y += fb.y * v4.y; Ov[3].z += fb.y * v4.z; Ov[3].w += fb.y * v4.w;
        }
    }

    __syncthreads();
#pragma unroll
    for (int i = 0; i < 4; ++i) red[qg * 4 + i][cg] = dsum[i];
    __syncthreads();
#pragma unroll
    for (int i = 0; i < 4; ++i) {
        float denom = 0.f;
#pragma unroll
        for (int c = 0; c < 16; ++c) denom += red[qg * 4 + i][c];
        float invd = 1.0f / denom;
        float4 o = make_float4(Ov[i].x * invd, Ov[i].y * invd,
                               Ov[i].z * invd, Ov[i].w * invd);
        *(float4*)&AO[((size_t)(b * 2048 + qr0 + qg * 4 + i)) * 1024 + h * 64 + cg * 4] = o;
    }
}

// =====================================================================
// Orchestration
// =====================================================================
extern "C" void kernel_launch(void* const* d_in, const int* in_sizes, int n_in,
                              void* d_out, int out_size, void* d_ws, size_t ws_size,
                              hipStream_t stream)
{
    const float* x   = (const float*)d_in[0];  // (2, 2048, 1024)
    const float* ctx = (const float*)d_in[1];  // (2, 1024, 768)
    const float* fam = (const float*)d_in[2];  // (1, 1024, 1024)
    const float* Wq  = (const float*)d_in[3];  // (1024, 1024)
    const float* Wk  = (const float*)d_in[4];  // (1024, 768)
    const float* Wv  = (const float*)d_in[5];  // (1024, 768)
    const float* Wo  = (const float*)d_in[6];  // (1024, 1024)
    const float* bo  = (const float*)d_in[7];  // (1024,)
    float* out = (float*)d_out;                // (2, 2048, 1024)

    char* p = (char*)d_ws;
    // fp32 intermediates
    float* q  = (float*)p; p += (size_t)4096 * 1024 * 4;
    float* kk = (float*)p; p += (size_t)2048 * 1024 * 4;
    float* vv = (float*)p; p += (size_t)2048 * 1024 * 4;
    float* G  = (float*)p; p += (size_t)2048 * 1024 * 4;
    float* ao = (float*)p; p += (size_t)4096 * 1024 * 4;
    // bf16 split planes (3 planes each, contiguous)
    const size_t nX  = (size_t)4096 * 1024;
    const size_t nC  = (size_t)2048 * 768;
    const size_t nWq = (size_t)1024 * 1024;
    const size_t nWk = (size_t)1024 * 768;
    const size_t nF  = (size_t)1024 * 1024;
    const size_t nKT = (size_t)2048 * 1024;
    unsigned short* xs  = (unsigned short*)p; p += nX  * 3 * 2;  // also reused for ao splits
    unsigned short* cs  = (unsigned short*)p; p += nC  * 3 * 2;
    unsigned short* wqs = (unsigned short*)p; p += nWq * 3 * 2;
    unsigned short* wks = (unsigned short*)p; p += nWk * 3 * 2;
    unsigned short* wvs = (unsigned short*)p; p += nWk * 3 * 2;
    unsigned short* wos = (unsigned short*)p; p += nWq * 3 * 2;
    unsigned short* fms = (unsigned short*)p; p += nF  * 3 * 2;
    unsigned short* kts = (unsigned short*)p; p += nKT * 3 * 2;

    // ---- split inputs into bf16x3 planes ----
    split3<<<1024, 256, 0, stream>>>(x,   xs,  nX);
    split3<<<512,  256, 0, stream>>>(ctx, cs,  nC);
    split3<<<256,  256, 0, stream>>>(Wq,  wqs, nWq);
    split3<<<256,  256, 0, stream>>>(Wk,  wks, nWk);
    split3<<<256,  256, 0, stream>>>(Wv,  wvs, nWk);
    split3<<<256,  256, 0, stream>>>(Wo,  wos, nWq);
    split3<<<256,  256, 0, stream>>>(fam, fms, nF);

    // ---- projections: fp32-grade bf16x3 MFMA GEMMs ----
    gemm_bt3<<<dim3(8, 32), 256, 0, stream>>>(xs, nX, wqs, nWq, nullptr, q,  4096, 1024, 1024);
    gemm_bt3<<<dim3(8, 16), 256, 0, stream>>>(cs, nC, wks, nWk, nullptr, kk, 2048, 1024, 768);
    gemm_bt3<<<dim3(8, 16), 256, 0, stream>>>(cs, nC, wvs, nWk, nullptr, vv, 2048, 1024, 768);

    // ---- k -> transposed splits; G_b = fam @ k_b  (as fam @ (k^T)^T) ----
    splitT3<<<dim3(32, 32, 2), 256, 0, stream>>>(kk, kts, nKT);
    gemm_bt3<<<dim3(8, 8), 256, 0, stream>>>(fms, nF, kts, nKT, nullptr, G, 1024, 1024, 1024);
    gemm_bt3<<<dim3(8, 8), 256, 0, stream>>>(fms, nF, kts + (size_t)1024 * 1024, nKT, nullptr,
                                             G + (size_t)1024 * 1024, 1024, 1024, 1024);

    // ---- fused FCA attention (fp32) ----
    attn_fused<<<dim3(32, 32), 256, 0, stream>>>(q, kk, vv, G, ao);

    // ---- output projection (reuse xs region for ao splits) ----
    split3<<<1024, 256, 0, stream>>>(ao, xs, nX);
    gemm_bt3<<<dim3(8, 32), 256, 0, stream>>>(xs, nX, wos, nWq, bo, out, 4096, 1024, 1024);
}

// Round 4
// 662.938 us; speedup vs baseline: 3.3613x; 1.5759x over previous
//
#include <hip/hip_runtime.h>
#include <hip/hip_fp16.h>
#include <hip/hip_bf16.h>
#include <math.h>

#define SCALE 0.125f   // 64^-0.5

typedef __attribute__((ext_vector_type(8))) short bf16x8;
typedef __attribute__((ext_vector_type(4))) float f32x4;

// ---------------------------------------------------------------------
// bf16 split helpers
// ---------------------------------------------------------------------
__device__ __forceinline__ unsigned short bf_bits(float x) {
    union { __hip_bfloat16 b; unsigned short u; } u;
    u.b = __float2bfloat16(x);
    return u.u;
}
__device__ __forceinline__ float bf_val(float x, unsigned short* bits) {
    union { __hip_bfloat16 b; unsigned short u; } u;
    u.b = __float2bfloat16(x);
    *bits = u.u;
    return __bfloat162float(u.b);
}

// fp32 -> 3 bf16 planes (hi, mid, lo); a == hi+mid+lo to >=24 mantissa bits
__global__ __launch_bounds__(256) void split3(
    const float* __restrict__ src, unsigned short* __restrict__ dst, size_t n)
{
    size_t i4 = ((size_t)blockIdx.x * 256 + threadIdx.x) * 4;
    size_t stride = (size_t)gridDim.x * 256 * 4;
    for (; i4 < n; i4 += stride) {
        float4 a = *(const float4*)&src[i4];
        float av[4] = {a.x, a.y, a.z, a.w};
        unsigned short hb[4], mb[4], lb[4];
#pragma unroll
        for (int j = 0; j < 4; ++j) {
            float fh = bf_val(av[j], &hb[j]);
            float r  = av[j] - fh;
            float fm = bf_val(r, &mb[j]);
            lb[j] = bf_bits(r - fm);
        }
        *(short4*)&dst[i4]       = make_short4(hb[0], hb[1], hb[2], hb[3]);
        *(short4*)&dst[i4 + n]   = make_short4(mb[0], mb[1], mb[2], mb[3]);
        *(short4*)&dst[i4 + 2*n] = make_short4(lb[0], lb[1], lb[2], lb[3]);
    }
}

// transpose + split3 for k: src fp32 [2][1024][1024] (j,n) -> planes (n,j)
__global__ __launch_bounds__(256) void splitT3(
    const float* __restrict__ src, unsigned short* __restrict__ dst, size_t plane)
{
    __shared__ float t[32][33];
    const int b  = blockIdx.z;
    const int j0 = blockIdx.y * 32;
    const int n0 = blockIdx.x * 32;
    const int tx = threadIdx.x & 31;
    const int ty = threadIdx.x >> 5;
    const float* s = src + (size_t)b * 1024 * 1024;
#pragma unroll
    for (int i = 0; i < 4; ++i)
        t[ty + 8*i][tx] = s[(size_t)(j0 + ty + 8*i) * 1024 + n0 + tx];
    __syncthreads();
#pragma unroll
    for (int i = 0; i < 4; ++i) {
        float a = t[tx][ty + 8*i];
        unsigned short hb, mb;
        float fh = bf_val(a, &hb);
        float r  = a - fh;
        float fm = bf_val(r, &mb);
        size_t o = (size_t)b * 1024 * 1024 + (size_t)(n0 + ty + 8*i) * 1024 + j0 + tx;
        dst[o]             = hb;
        dst[o + plane]     = mb;
        dst[o + 2 * plane] = bf_bits(r - fm);
    }
}

// transpose + split2 for v: src fp32 [2][1024 c][1024 hd] -> 2 planes [(b*1024+hd)][c]
__global__ __launch_bounds__(256) void splitT2(
    const float* __restrict__ src, unsigned short* __restrict__ dst, size_t plane)
{
    __shared__ float t[32][33];
    const int b  = blockIdx.z;
    const int r0 = blockIdx.y * 32;   // src row (c)
    const int c0 = blockIdx.x * 32;   // src col (hd)
    const int tx = threadIdx.x & 31;
    const int ty = threadIdx.x >> 5;
    const float* s = src + (size_t)b * 1024 * 1024;
#pragma unroll
    for (int i = 0; i < 4; ++i)
        t[ty + 8*i][tx] = s[(size_t)(r0 + ty + 8*i) * 1024 + c0 + tx];
    __syncthreads();
#pragma unroll
    for (int i = 0; i < 4; ++i) {
        float a = t[tx][ty + 8*i];    // src[r0+tx][c0+ty+8i]
        unsigned short hb, mb;
        float fh = bf_val(a, &hb);
        mb = bf_bits(a - fh);
        size_t o = (size_t)b * 1024 * 1024 + (size_t)(c0 + ty + 8*i) * 1024 + r0 + tx;
        dst[o]         = hb;
        dst[o + plane] = mb;
    }
}

// ---------------------------------------------------------------------
// gemm_bt3: C[M,N] = A @ B^T (+bias), fp32-grade via bf16x3 splits.
// (unchanged from round 3 — validated)
// ---------------------------------------------------------------------
__global__ __launch_bounds__(256) void gemm_bt3(
    const unsigned short* __restrict__ A, size_t Aplane,
    const unsigned short* __restrict__ B, size_t Bplane,
    const float* __restrict__ bias, float* __restrict__ C,
    int M, int N, int K)
{
    __shared__ __align__(16) unsigned short Ash[3][128 * 32];
    __shared__ __align__(16) unsigned short Bsh[3][128 * 32];

    const int tid  = threadIdx.x;
    const int m0   = blockIdx.y * 128;
    const int n0   = blockIdx.x * 128;
    const int w    = tid >> 6;
    const int lane = tid & 63;
    const int wm   = (w >> 1) * 64;
    const int wn   = (w & 1) * 64;
    const int lq   = lane >> 4;
    const int l15  = lane & 15;

    const int srow = tid >> 2;
    const int sc8  = (tid & 3) * 8;

    f32x4 acc[4][4];
#pragma unroll
    for (int mi = 0; mi < 4; ++mi)
#pragma unroll
        for (int ni = 0; ni < 4; ++ni) {
            acc[mi][ni].x = 0.f; acc[mi][ni].y = 0.f;
            acc[mi][ni].z = 0.f; acc[mi][ni].w = 0.f;
        }

    for (int k0 = 0; k0 < K; k0 += 32) {
        __syncthreads();
#pragma unroll
        for (int p = 0; p < 3; ++p) {
            const unsigned short* Ap = A + (size_t)p * Aplane;
            const unsigned short* Bp = B + (size_t)p * Bplane;
            *(float4*)&Ash[p][srow * 32 + sc8] =
                *(const float4*)&Ap[(size_t)(m0 + srow) * K + k0 + sc8];
            *(float4*)&Ash[p][(srow + 64) * 32 + sc8] =
                *(const float4*)&Ap[(size_t)(m0 + srow + 64) * K + k0 + sc8];
            *(float4*)&Bsh[p][srow * 32 + sc8] =
                *(const float4*)&Bp[(size_t)(n0 + srow) * K + k0 + sc8];
            *(float4*)&Bsh[p][(srow + 64) * 32 + sc8] =
                *(const float4*)&Bp[(size_t)(n0 + srow + 64) * K + k0 + sc8];
        }
        __syncthreads();

#pragma unroll
        for (int ap = 0; ap < 3; ++ap) {
            bf16x8 af[4];
#pragma unroll
            for (int mi = 0; mi < 4; ++mi)
                af[mi] = *(const bf16x8*)&Ash[ap][(wm + mi * 16 + l15) * 32 + lq * 8];
#pragma unroll
            for (int bp = 0; bp < 3 - ap; ++bp) {
                bf16x8 bfr[4];
#pragma unroll
                for (int ni = 0; ni < 4; ++ni)
                    bfr[ni] = *(const bf16x8*)&Bsh[bp][(wn + ni * 16 + l15) * 32 + lq * 8];
#pragma unroll
                for (int mi = 0; mi < 4; ++mi)
#pragma unroll
                    for (int ni = 0; ni < 4; ++ni)
                        acc[mi][ni] = __builtin_amdgcn_mfma_f32_16x16x32_bf16(
                            af[mi], bfr[ni], acc[mi][ni], 0, 0, 0);
            }
        }
    }

#pragma unroll
    for (int mi = 0; mi < 4; ++mi) {
#pragma unroll
        for (int ni = 0; ni < 4; ++ni) {
            int row = m0 + wm + mi * 16 + lq * 4;
            int col = n0 + wn + ni * 16 + l15;
            float bb = bias ? bias[col] : 0.f;
            C[(size_t)(row + 0) * N + col] = acc[mi][ni].x + bb;
            C[(size_t)(row + 1) * N + col] = acc[mi][ni].y + bb;
            C[(size_t)(row + 2) * N + col] = acc[mi][ni].z + bb;
            C[(size_t)(row + 3) * N + col] = acc[mi][ni].w + bb;
        }
    }
}

// ---------------------------------------------------------------------
// MFMA fused FCA attention.
// Block = 64 q-rows of one (b,h), 256 thr = 4 waves (2x2 over q/c).
// fw: Q3 x G3, 6 products (fp32-grade -> threshold-safe).
// sim: Q2 x K2, 3 products. PV: P(bf16) x V2, 2 products.
// LDS: Q3(24K) + K2(16K, reused for Vt) + G3(24K, overlaid by Ps+dsum).
// 8-quad XOR swizzle on all 64-wide bf16 tiles -> <=2-way banking.
// ---------------------------------------------------------------------
#define LX(r, qd) (((r) << 6) + (((qd) ^ ((r) & 7)) << 3))

__global__ __launch_bounds__(256) void attn_mfma(
    const unsigned short* __restrict__ Qp,  // 3 planes, stride nQ, [4096][1024]
    const unsigned short* __restrict__ Kp,  // 3 planes, stride nK, [2048][1024] (hi,mid used)
    const unsigned short* __restrict__ Gp,  // 3 planes, stride nK
    const unsigned short* __restrict__ Vp,  // 2 planes, stride nK, [(b*1024+hd)][c]
    float* __restrict__ AO)
{
    const size_t nQ = (size_t)4096 * 1024;
    const size_t nK = (size_t)2048 * 1024;

    __shared__ __align__(16) unsigned short Qsh[3][4096];
    __shared__ __align__(16) unsigned short Ksh[2][4096];
    __shared__ __align__(16) unsigned short Gsh[3][4096];

    const int tid = threadIdx.x;
    const int bh = blockIdx.y;
    const int b = bh >> 4, h = bh & 15;
    const int qr0 = blockIdx.x * 64;

    const int w = tid >> 6, lane = tid & 63;
    const int lq = lane >> 4, l15 = lane & 15;
    const int wm = (w >> 1) * 32;   // q-offset
    const int wn = (w & 1) * 32;    // c-offset (sim/fw) / d-offset (PV)

    const unsigned short* qg = Qp + ((size_t)(b * 2048 + qr0)) * 1024 + h * 64;
    const unsigned short* kg = Kp + ((size_t)(b * 1024)) * 1024 + h * 64;
    const unsigned short* gg = Gp + ((size_t)(b * 1024)) * 1024 + h * 64;
    const unsigned short* vg = Vp + ((size_t)(b * 1024)) * 1024;  // row hd=h*64+d

    // ---- stage Q (3 planes) ----
#pragma unroll
    for (int i = 0; i < 2; ++i) {
        int id = tid + i * 256;
        int r = id >> 3, qd = id & 7, lx = LX(r, qd);
        size_t grow = (size_t)r * 1024 + qd * 8;
        *(float4*)&Qsh[0][lx] = *(const float4*)&qg[grow];
        *(float4*)&Qsh[1][lx] = *(const float4*)&qg[nQ + grow];
        *(float4*)&Qsh[2][lx] = *(const float4*)&qg[2 * nQ + grow];
    }

    // ---------------- pass 1: rowmax of min(|fw|,1) ----------------
    float mx[2][4];
#pragma unroll
    for (int ti = 0; ti < 2; ++ti)
#pragma unroll
        for (int r = 0; r < 4; ++r) mx[ti][r] = 0.f;

    for (int jt = 0; jt < 16; ++jt) {
        __syncthreads();
#pragma unroll
        for (int i = 0; i < 2; ++i) {
            int id = tid + i * 256;
            int r = id >> 3, qd = id & 7, lx = LX(r, qd);
            size_t grow = (size_t)(jt * 64 + r) * 1024 + qd * 8;
            *(float4*)&Gsh[0][lx] = *(const float4*)&gg[grow];
            *(float4*)&Gsh[1][lx] = *(const float4*)&gg[nK + grow];
            *(float4*)&Gsh[2][lx] = *(const float4*)&gg[2 * nK + grow];
        }
        __syncthreads();

        f32x4 afw[2][2];
#pragma unroll
        for (int ti = 0; ti < 2; ++ti)
#pragma unroll
            for (int tj = 0; tj < 2; ++tj) {
                afw[ti][tj].x = 0.f; afw[ti][tj].y = 0.f;
                afw[ti][tj].z = 0.f; afw[ti][tj].w = 0.f;
            }

#pragma unroll
        for (int kc = 0; kc < 2; ++kc) {
            bf16x8 aq[3][2], bg[3][2];
#pragma unroll
            for (int ti = 0; ti < 2; ++ti) {
                int lx = LX(wm + ti * 16 + l15, kc * 4 + lq);
                aq[0][ti] = *(const bf16x8*)&Qsh[0][lx];
                aq[1][ti] = *(const bf16x8*)&Qsh[1][lx];
                aq[2][ti] = *(const bf16x8*)&Qsh[2][lx];
            }
#pragma unroll
            for (int tj = 0; tj < 2; ++tj) {
                int lx = LX(wn + tj * 16 + l15, kc * 4 + lq);
                bg[0][tj] = *(const bf16x8*)&Gsh[0][lx];
                bg[1][tj] = *(const bf16x8*)&Gsh[1][lx];
                bg[2][tj] = *(const bf16x8*)&Gsh[2][lx];
            }
#pragma unroll
            for (int ti = 0; ti < 2; ++ti)
#pragma unroll
                for (int tj = 0; tj < 2; ++tj) {
                    f32x4 a = afw[ti][tj];
                    a = __builtin_amdgcn_mfma_f32_16x16x32_bf16(aq[0][ti], bg[0][tj], a, 0, 0, 0);
                    a = __builtin_amdgcn_mfma_f32_16x16x32_bf16(aq[0][ti], bg[1][tj], a, 0, 0, 0);
                    a = __builtin_amdgcn_mfma_f32_16x16x32_bf16(aq[1][ti], bg[0][tj], a, 0, 0, 0);
                    a = __builtin_amdgcn_mfma_f32_16x16x32_bf16(aq[1][ti], bg[1][tj], a, 0, 0, 0);
                    a = __builtin_amdgcn_mfma_f32_16x16x32_bf16(aq[0][ti], bg[2][tj], a, 0, 0, 0);
                    a = __builtin_amdgcn_mfma_f32_16x16x32_bf16(aq[2][ti], bg[0][tj], a, 0, 0, 0);
                    afw[ti][tj] = a;
                }
        }
#pragma unroll
        for (int ti = 0; ti < 2; ++ti)
#pragma unroll
            for (int tj = 0; tj < 2; ++tj)
#pragma unroll
                for (int r = 0; r < 4; ++r)
                    mx[ti][r] = fmaxf(mx[ti][r], fminf(fabsf(afw[ti][tj][r] * SCALE), 1.f));
    }
    // butterfly-max over the 16 l15 lanes
#pragma unroll
    for (int ti = 0; ti < 2; ++ti)
#pragma unroll
        for (int r = 0; r < 4; ++r) {
#pragma unroll
            for (int d = 1; d < 16; d <<= 1)
                mx[ti][r] = fmaxf(mx[ti][r], __shfl_xor(mx[ti][r], d, 64));
        }
    float* rmxp = (float*)&Ksh[0][0];
    if (l15 == 0) {
#pragma unroll
        for (int ti = 0; ti < 2; ++ti)
#pragma unroll
            for (int r = 0; r < 4; ++r)
                rmxp[(w & 1) * 64 + wm + ti * 16 + lq * 4 + r] = mx[ti][r];
    }
    __syncthreads();
    float inv[2][4];
#pragma unroll
    for (int ti = 0; ti < 2; ++ti)
#pragma unroll
        for (int r = 0; r < 4; ++r) {
            int row = wm + ti * 16 + lq * 4 + r;
            float m = fmaxf(rmxp[row], rmxp[64 + row]);
            inv[ti][r] = 1.0f / (m + 1e-6f);
        }
    __syncthreads();   // before pass-2 staging clobbers Ksh

    // ---------------- pass 2: attention ----------------
    f32x4 aco[2][2];
#pragma unroll
    for (int ti = 0; ti < 2; ++ti)
#pragma unroll
        for (int tj = 0; tj < 2; ++tj) {
            aco[ti][tj].x = 0.f; aco[ti][tj].y = 0.f;
            aco[ti][tj].z = 0.f; aco[ti][tj].w = 0.f;
        }
    float dsum[2][4];
#pragma unroll
    for (int ti = 0; ti < 2; ++ti)
#pragma unroll
        for (int r = 0; r < 4; ++r) dsum[ti][r] = 0.f;

    unsigned short* Ps = &Gsh[0][0];                    // [64][72] bf16 overlay
    float* dsp = (float*)(&Gsh[0][0] + 64 * 72);        // 128 floats, after Ps

    for (int jt = 0; jt < 16; ++jt) {
        __syncthreads();
#pragma unroll
        for (int i = 0; i < 2; ++i) {
            int id = tid + i * 256;
            int r = id >> 3, qd = id & 7, lx = LX(r, qd);
            size_t grow = (size_t)(jt * 64 + r) * 1024 + qd * 8;
            *(float4*)&Ksh[0][lx] = *(const float4*)&kg[grow];
            *(float4*)&Ksh[1][lx] = *(const float4*)&kg[nK + grow];
            *(float4*)&Gsh[0][lx] = *(const float4*)&gg[grow];
            *(float4*)&Gsh[1][lx] = *(const float4*)&gg[nK + grow];
            *(float4*)&Gsh[2][lx] = *(const float4*)&gg[2 * nK + grow];
        }
        __syncthreads();

        f32x4 as_[2][2], af[2][2];
#pragma unroll
        for (int ti = 0; ti < 2; ++ti)
#pragma unroll
            for (int tj = 0; tj < 2; ++tj) {
                as_[ti][tj].x = 0.f; as_[ti][tj].y = 0.f;
                as_[ti][tj].z = 0.f; as_[ti][tj].w = 0.f;
                af[ti][tj].x = 0.f; af[ti][tj].y = 0.f;
                af[ti][tj].z = 0.f; af[ti][tj].w = 0.f;
            }

#pragma unroll
        for (int kc = 0; kc < 2; ++kc) {
            bf16x8 aq[3][2], bk[2][2], bg[3][2];
#pragma unroll
            for (int ti = 0; ti < 2; ++ti) {
                int lx = LX(wm + ti * 16 + l15, kc * 4 + lq);
                aq[0][ti] = *(const bf16x8*)&Qsh[0][lx];
                aq[1][ti] = *(const bf16x8*)&Qsh[1][lx];
                aq[2][ti] = *(const bf16x8*)&Qsh[2][lx];
            }
#pragma unroll
            for (int tj = 0; tj < 2; ++tj) {
                int lx = LX(wn + tj * 16 + l15, kc * 4 + lq);
                bk[0][tj] = *(const bf16x8*)&Ksh[0][lx];
                bk[1][tj] = *(const bf16x8*)&Ksh[1][lx];
                bg[0][tj] = *(const bf16x8*)&Gsh[0][lx];
                bg[1][tj] = *(const bf16x8*)&Gsh[1][lx];
                bg[2][tj] = *(const bf16x8*)&Gsh[2][lx];
            }
#pragma unroll
            for (int ti = 0; ti < 2; ++ti)
#pragma unroll
                for (int tj = 0; tj < 2; ++tj) {
                    f32x4 s = as_[ti][tj];
                    s = __builtin_amdgcn_mfma_f32_16x16x32_bf16(aq[0][ti], bk[0][tj], s, 0, 0, 0);
                    s = __builtin_amdgcn_mfma_f32_16x16x32_bf16(aq[0][ti], bk[1][tj], s, 0, 0, 0);
                    s = __builtin_amdgcn_mfma_f32_16x16x32_bf16(aq[1][ti], bk[0][tj], s, 0, 0, 0);
                    as_[ti][tj] = s;
                    f32x4 a = af[ti][tj];
                    a = __builtin_amdgcn_mfma_f32_16x16x32_bf16(aq[0][ti], bg[0][tj], a, 0, 0, 0);
                    a = __builtin_amdgcn_mfma_f32_16x16x32_bf16(aq[0][ti], bg[1][tj], a, 0, 0, 0);
                    a = __builtin_amdgcn_mfma_f32_16x16x32_bf16(aq[1][ti], bg[0][tj], a, 0, 0, 0);
                    a = __builtin_amdgcn_mfma_f32_16x16x32_bf16(aq[1][ti], bg[1][tj], a, 0, 0, 0);
                    a = __builtin_amdgcn_mfma_f32_16x16x32_bf16(aq[0][ti], bg[2][tj], a, 0, 0, 0);
                    a = __builtin_amdgcn_mfma_f32_16x16x32_bf16(aq[2][ti], bg[0][tj], a, 0, 0, 0);
                    af[ti][tj] = a;
                }
        }

        // threshold + exp (bf16-consistent e for numerator & denominator)
        unsigned short eb[2][2][4];
#pragma unroll
        for (int ti = 0; ti < 2; ++ti)
#pragma unroll
            for (int tj = 0; tj < 2; ++tj)
#pragma unroll
                for (int r = 0; r < 4; ++r) {
                    float fn = fminf(fabsf(af[ti][tj][r] * SCALE), 1.f) * inv[ti][r];
                    float pen = (fn > 0.6f) ? 0.f : -50.f;
                    float e = __expf(as_[ti][tj][r] * SCALE + pen);
                    unsigned short bits;
                    float er = bf_val(e, &bits);
                    eb[ti][tj][r] = bits;
                    dsum[ti][r] += er;
                }
        __syncthreads();   // all waves done reading Gsh/Ksh for this jt

        // write P (bf16) into Ps[q][c] (pad 72) + stage Vt into Ksh
#pragma unroll
        for (int ti = 0; ti < 2; ++ti)
#pragma unroll
            for (int tj = 0; tj < 2; ++tj)
#pragma unroll
                for (int r = 0; r < 4; ++r) {
                    int qq = wm + ti * 16 + lq * 4 + r;
                    int cc = wn + tj * 16 + l15;
                    Ps[qq * 72 + cc] = eb[ti][tj][r];
                }
#pragma unroll
        for (int i = 0; i < 2; ++i) {
            int id = tid + i * 256;
            int r = id >> 3, qd = id & 7, lx = LX(r, qd);
            size_t grow = (size_t)(h * 64 + r) * 1024 + jt * 64 + qd * 8;
            *(float4*)&Ksh[0][lx] = *(const float4*)&vg[grow];
            *(float4*)&Ksh[1][lx] = *(const float4*)&vg[nK + grow];
        }
        __syncthreads();

        // PV: O[q][d] += P[q][c] * V[c][d]
#pragma unroll
        for (int kc = 0; kc < 2; ++kc) {
            bf16x8 ap_[2], bv[2][2];
#pragma unroll
            for (int ti = 0; ti < 2; ++ti)
                ap_[ti] = *(const bf16x8*)&Ps[(wm + ti * 16 + l15) * 72 + kc * 32 + lq * 8];
#pragma unroll
            for (int tj = 0; tj < 2; ++tj) {
                int lx = LX(wn + tj * 16 + l15, kc * 4 + lq);
                bv[0][tj] = *(const bf16x8*)&Ksh[0][lx];
                bv[1][tj] = *(const bf16x8*)&Ksh[1][lx];
            }
#pragma unroll
            for (int ti = 0; ti < 2; ++ti)
#pragma unroll
                for (int tj = 0; tj < 2; ++tj) {
                    f32x4 o = aco[ti][tj];
                    o = __builtin_amdgcn_mfma_f32_16x16x32_bf16(ap_[ti], bv[0][tj], o, 0, 0, 0);
                    o = __builtin_amdgcn_mfma_f32_16x16x32_bf16(ap_[ti], bv[1][tj], o, 0, 0, 0);
                    aco[ti][tj] = o;
                }
        }
    }

    // denominator: butterfly-sum over l15, combine wave halves via LDS
#pragma unroll
    for (int ti = 0; ti < 2; ++ti)
#pragma unroll
        for (int r = 0; r < 4; ++r) {
#pragma unroll
            for (int d = 1; d < 16; d <<= 1)
                dsum[ti][r] += __shfl_xor(dsum[ti][r], d, 64);
        }
    __syncthreads();
    if (l15 == 0) {
#pragma unroll
        for (int ti = 0; ti < 2; ++ti)
#pragma unroll
            for (int r = 0; r < 4; ++r)
                dsp[(w & 1) * 64 + wm + ti * 16 + lq * 4 + r] = dsum[ti][r];
    }
    __syncthreads();
#pragma unroll
    for (int ti = 0; ti < 2; ++ti) {
        float invd[4];
#pragma unroll
        for (int r = 0; r < 4; ++r) {
            int row = wm + ti * 16 + lq * 4 + r;
            invd[r] = 1.0f / (dsp[row] + dsp[64 + row]);
        }
#pragma unroll
        for (int tj = 0; tj < 2; ++tj)
#pragma unroll
            for (int r = 0; r < 4; ++r) {
                int qq = qr0 + wm + ti * 16 + lq * 4 + r;
                int dd = h * 64 + wn + tj * 16 + l15;
                AO[(size_t)(b * 2048 + qq) * 1024 + dd] = aco[ti][tj][r] * invd[r];
            }
    }
}

// =====================================================================
// Orchestration
// =====================================================================
extern "C" void kernel_launch(void* const* d_in, const int* in_sizes, int n_in,
                              void* d_out, int out_size, void* d_ws, size_t ws_size,
                              hipStream_t stream)
{
    const float* x   = (const float*)d_in[0];
    const float* ctx = (const float*)d_in[1];
    const float* fam = (const float*)d_in[2];
    const float* Wq  = (const float*)d_in[3];
    const float* Wk  = (const float*)d_in[4];
    const float* Wv  = (const float*)d_in[5];
    const float* Wo  = (const float*)d_in[6];
    const float* bo  = (const float*)d_in[7];
    float* out = (float*)d_out;

    const size_t nX  = (size_t)4096 * 1024;
    const size_t nC  = (size_t)2048 * 768;
    const size_t nWq = (size_t)1024 * 1024;
    const size_t nWk = (size_t)1024 * 768;
    const size_t nF  = (size_t)1024 * 1024;
    const size_t nKT = (size_t)2048 * 1024;

    char* p = (char*)d_ws;
    float* q  = (float*)p; p += nX  * 4;   // fp32 q; later reused as ao
    float* kk = (float*)p; p += nKT * 4;
    float* vv = (float*)p; p += nKT * 4;
    float* G  = (float*)p; p += nKT * 4;
    // SH: shared region for x-splits -> q-splits -> ao-splits (3 planes of nX)
    unsigned short* SH  = (unsigned short*)p; p += nX  * 3 * 2;
    unsigned short* cs  = (unsigned short*)p; p += nC  * 3 * 2;
    unsigned short* wqs = (unsigned short*)p; p += nWq * 3 * 2;
    unsigned short* wks = (unsigned short*)p; p += nWk * 3 * 2;
    unsigned short* wvs = (unsigned short*)p; p += nWk * 3 * 2;
    unsigned short* wos = (unsigned short*)p; p += nWq * 3 * 2;
    unsigned short* fms = (unsigned short*)p; p += nF  * 3 * 2;
    unsigned short* kts = (unsigned short*)p; p += nKT * 3 * 2;
    unsigned short* ksp = (unsigned short*)p; p += nKT * 3 * 2;
    unsigned short* gsp = (unsigned short*)p; p += nKT * 3 * 2;
    unsigned short* vts = (unsigned short*)p; p += nKT * 2 * 2;
    float* ao = q;   // q fp32 dead after its split

    // ---- input splits ----
    split3<<<1024, 256, 0, stream>>>(x,   SH,  nX);
    split3<<<512,  256, 0, stream>>>(ctx, cs,  nC);
    split3<<<256,  256, 0, stream>>>(Wq,  wqs, nWq);
    split3<<<256,  256, 0, stream>>>(Wk,  wks, nWk);
    split3<<<256,  256, 0, stream>>>(Wv,  wvs, nWk);
    split3<<<256,  256, 0, stream>>>(Wo,  wos, nWq);
    split3<<<256,  256, 0, stream>>>(fam, fms, nF);

    // ---- projections ----
    gemm_bt3<<<dim3(8, 32), 256, 0, stream>>>(SH, nX, wqs, nWq, nullptr, q,  4096, 1024, 1024);
    gemm_bt3<<<dim3(8, 16), 256, 0, stream>>>(cs, nC, wks, nWk, nullptr, kk, 2048, 1024, 768);
    gemm_bt3<<<dim3(8, 16), 256, 0, stream>>>(cs, nC, wvs, nWk, nullptr, vv, 2048, 1024, 768);

    // q -> bf16x3 planes (SH reused; x-splits dead after q-projection)
    split3<<<1024, 256, 0, stream>>>(q, SH, nX);

    // ---- G = fam @ k_b (via transposed-split k) ----
    splitT3<<<dim3(32, 32, 2), 256, 0, stream>>>(kk, kts, nKT);
    gemm_bt3<<<dim3(8, 8), 256, 0, stream>>>(fms, nF, kts, nKT, nullptr, G, 1024, 1024, 1024);
    gemm_bt3<<<dim3(8, 8), 256, 0, stream>>>(fms, nF, kts + (size_t)1024 * 1024, nKT, nullptr,
                                             G + (size_t)1024 * 1024, 1024, 1024, 1024);

    // ---- attention input splits ----
    split3<<<512, 256, 0, stream>>>(kk, ksp, nKT);
    split3<<<512, 256, 0, stream>>>(G,  gsp, nKT);
    splitT2<<<dim3(32, 32, 2), 256, 0, stream>>>(vv, vts, nKT);

    // ---- MFMA fused FCA attention (writes ao = q buffer) ----
    attn_mfma<<<dim3(32, 32), 256, 0, stream>>>(SH, ksp, gsp, vts, ao);

    // ---- output projection ----
    split3<<<1024, 256, 0, stream>>>(ao, SH, nX);
    gemm_bt3<<<dim3(8, 32), 256, 0, stream>>>(SH, nX, wos, nWq, bo, out, 4096, 1024, 1024);
}

// Round 5
// 575.938 us; speedup vs baseline: 3.8690x; 1.1511x over previous
//
#include <hip/hip_runtime.h>
#include <hip/hip_fp16.h>
#include <math.h>

#define SCALE 0.125f   // 64^-0.5

typedef _Float16 f16;
typedef __attribute__((ext_vector_type(8))) _Float16 f16x8;
typedef __attribute__((ext_vector_type(4))) float f32x4;

// =====================================================================
// split2: fp32 -> 2 fp16 planes (h, l), with exact power-of-2 pre-scale.
// a*s == h + l to ~22 mantissa bits. Weights use s=64 (keeps l-plane out
// of fp16-subnormal range); activations s=1. GEMM epilogue descales.
// =====================================================================
__global__ __launch_bounds__(256) void split2(
    const float* __restrict__ src, f16* __restrict__ h, f16* __restrict__ l,
    float scale, size_t n)
{
    size_t i4 = ((size_t)blockIdx.x * 256 + threadIdx.x) * 4;
    size_t stride = (size_t)gridDim.x * 256 * 4;
    for (; i4 < n; i4 += stride) {
        float4 a = *(const float4*)&src[i4];
        float av[4] = {a.x * scale, a.y * scale, a.z * scale, a.w * scale};
        f16 hv[4], lv[4];
#pragma unroll
        for (int j = 0; j < 4; ++j) {
            hv[j] = (f16)av[j];
            lv[j] = (f16)(av[j] - (float)hv[j]);
        }
        *(float2*)&h[i4] = *(float2*)hv;
        *(float2*)&l[i4] = *(float2*)lv;
    }
}

// =====================================================================
// gemm16: C[M,N] = A[M,K] @ B[N,K]^T via fp16x2 planes, 3 MFMA products
// (hh + hl + lh; dropped ll term is O(2^-22)). fp32 accumulate.
// B rows strided by Bstr (>=K) to support batch slices of transposed
// planes. Outputs (any subset, wave-uniform null checks):
//   Cf      : fp32 (+bias), scaled by oscale
//   Ch/Cl   : fp16x2 planes, row-major [M][N]
//   Cth/Ctl : fp16x2 planes, transposed [N][Mt] (row stride Mt)
// Tile 128x128, BK=32, 256 thr = 4 waves (2x2 of 64x64).
// LDS granule-XOR swizzle: 4x 16B granules/row, g' = g ^ (row&3)
// -> fragment reads 2-way (free) instead of 8-way.
// =====================================================================
#define GX(r, g) (((r) << 5) + ((((g) ^ ((r) & 3))) << 3))

__global__ __launch_bounds__(256) void gemm16(
    const f16* __restrict__ Ah, const f16* __restrict__ Al,
    const f16* __restrict__ Bh, const f16* __restrict__ Bl, int Bstr,
    float* __restrict__ Cf, const float* __restrict__ bias,
    f16* __restrict__ Ch, f16* __restrict__ Cl,
    f16* __restrict__ Cth, f16* __restrict__ Ctl, int Mt,
    float oscale, int M, int N, int K)
{
    __shared__ __align__(16) f16 Ash[2][128 * 32];
    __shared__ __align__(16) f16 Bsh[2][128 * 32];

    const int tid  = threadIdx.x;
    const int m0   = blockIdx.y * 128;
    const int n0   = blockIdx.x * 128;
    const int w    = tid >> 6;
    const int lane = tid & 63;
    const int wm   = (w >> 1) * 64;
    const int wn   = (w & 1) * 64;
    const int lq   = lane >> 4;
    const int l15  = lane & 15;

    const int srow = tid >> 2;       // 0..63
    const int sg   = tid & 3;        // granule 0..3 (8 f16 each)

    f32x4 acc[4][4];
#pragma unroll
    for (int mi = 0; mi < 4; ++mi)
#pragma unroll
        for (int ni = 0; ni < 4; ++ni) {
            acc[mi][ni].x = 0.f; acc[mi][ni].y = 0.f;
            acc[mi][ni].z = 0.f; acc[mi][ni].w = 0.f;
        }

    for (int k0 = 0; k0 < K; k0 += 32) {
        __syncthreads();
        {
            size_t a0 = (size_t)(m0 + srow) * K + k0 + sg * 8;
            size_t a1 = (size_t)(m0 + srow + 64) * K + k0 + sg * 8;
            size_t b0 = (size_t)(n0 + srow) * Bstr + k0 + sg * 8;
            size_t b1 = (size_t)(n0 + srow + 64) * Bstr + k0 + sg * 8;
            *(float4*)&Ash[0][GX(srow, sg)]      = *(const float4*)&Ah[a0];
            *(float4*)&Ash[0][GX(srow + 64, sg)] = *(const float4*)&Ah[a1];
            *(float4*)&Ash[1][GX(srow, sg)]      = *(const float4*)&Al[a0];
            *(float4*)&Ash[1][GX(srow + 64, sg)] = *(const float4*)&Al[a1];
            *(float4*)&Bsh[0][GX(srow, sg)]      = *(const float4*)&Bh[b0];
            *(float4*)&Bsh[0][GX(srow + 64, sg)] = *(const float4*)&Bh[b1];
            *(float4*)&Bsh[1][GX(srow, sg)]      = *(const float4*)&Bl[b0];
            *(float4*)&Bsh[1][GX(srow + 64, sg)] = *(const float4*)&Bl[b1];
        }
        __syncthreads();

        f16x8 afh[4], afl[4];
#pragma unroll
        for (int mi = 0; mi < 4; ++mi) {
            int r = wm + mi * 16 + l15;
            afh[mi] = *(const f16x8*)&Ash[0][GX(r, lq)];
            afl[mi] = *(const f16x8*)&Ash[1][GX(r, lq)];
        }
#pragma unroll
        for (int ni = 0; ni < 4; ++ni) {
            int r = wn + ni * 16 + l15;
            f16x8 bh = *(const f16x8*)&Bsh[0][GX(r, lq)];
            f16x8 bl = *(const f16x8*)&Bsh[1][GX(r, lq)];
#pragma unroll
            for (int mi = 0; mi < 4; ++mi) {
                f32x4 a = acc[mi][ni];
                a = __builtin_amdgcn_mfma_f32_16x16x32_f16(afh[mi], bh, a, 0, 0, 0);
                a = __builtin_amdgcn_mfma_f32_16x16x32_f16(afh[mi], bl, a, 0, 0, 0);
                a = __builtin_amdgcn_mfma_f32_16x16x32_f16(afl[mi], bh, a, 0, 0, 0);
                acc[mi][ni] = a;
            }
        }
    }

#pragma unroll
    for (int mi = 0; mi < 4; ++mi) {
#pragma unroll
        for (int ni = 0; ni < 4; ++ni) {
            int row = m0 + wm + mi * 16 + lq * 4;
            int col = n0 + wn + ni * 16 + l15;
            float v[4];
#pragma unroll
            for (int r = 0; r < 4; ++r) v[r] = acc[mi][ni][r] * oscale;
            if (Cf) {
                float bb = bias ? bias[col] : 0.f;
#pragma unroll
                for (int r = 0; r < 4; ++r)
                    Cf[(size_t)(row + r) * N + col] = v[r] + bb;
            }
            if (Ch) {
#pragma unroll
                for (int r = 0; r < 4; ++r) {
                    f16 hh = (f16)v[r];
                    Ch[(size_t)(row + r) * N + col] = hh;
                    Cl[(size_t)(row + r) * N + col] = (f16)(v[r] - (float)hh);
                }
            }
            if (Cth) {
                union { f16 a[4]; float2 f; } uh, ul;
#pragma unroll
                for (int r = 0; r < 4; ++r) {
                    uh.a[r] = (f16)v[r];
                    ul.a[r] = (f16)(v[r] - (float)uh.a[r]);
                }
                *(float2*)&Cth[(size_t)col * Mt + row] = uh.f;
                *(float2*)&Ctl[(size_t)col * Mt + row] = ul.f;
            }
        }
    }
}

// =====================================================================
// MFMA fused FCA attention, fp16x2 planes.
// fw: Q2 x G2, 3 products (2^-22-grade -> threshold-safe).
// sim: Q2 x K2, 3 products. PV: P(fp16) x V2, 2 products.
// LDS 48 KB -> 3 blocks/CU. Row = 64 f16 = 8x16B granules, XOR swizzle.
// Output written directly as fp16x2 planes (feeds out-projection).
// =====================================================================
#define LX(r, qd) (((r) << 6) + ((((qd) ^ ((r) & 7))) << 3))

__global__ __launch_bounds__(256) void attn_mfma(
    const f16* __restrict__ Qh, const f16* __restrict__ Ql,
    const f16* __restrict__ Kh, const f16* __restrict__ Kl,
    const f16* __restrict__ Gh, const f16* __restrict__ Gl,
    const f16* __restrict__ Vth, const f16* __restrict__ Vtl,
    f16* __restrict__ AOh, f16* __restrict__ AOl)
{
    __shared__ __align__(16) f16 Qsh[2][4096];
    __shared__ __align__(16) f16 Ksh[2][4096];
    __shared__ __align__(16) f16 Gsh[2][4096];

    const int tid = threadIdx.x;
    const int bh = blockIdx.y;
    const int b = bh >> 4, h = bh & 15;
    const int qr0 = blockIdx.x * 64;

    const int w = tid >> 6, lane = tid & 63;
    const int lq = lane >> 4, l15 = lane & 15;
    const int wm = (w >> 1) * 32;   // q-offset
    const int wn = (w & 1) * 32;    // c-offset / d-offset

    const size_t qb = ((size_t)(b * 2048 + qr0)) * 1024 + h * 64;
    const size_t kb = ((size_t)(b * 1024)) * 1024 + h * 64;

    // ---- stage Q (2 planes) ----
#pragma unroll
    for (int i = 0; i < 2; ++i) {
        int id = tid + i * 256;
        int r = id >> 3, qd = id & 7, lx = LX(r, qd);
        size_t g = qb + (size_t)r * 1024 + qd * 8;
        *(float4*)&Qsh[0][lx] = *(const float4*)&Qh[g];
        *(float4*)&Qsh[1][lx] = *(const float4*)&Ql[g];
    }

    // ---------------- pass 1: rowmax of min(|fw|,1) ----------------
    float mx[2][4];
#pragma unroll
    for (int ti = 0; ti < 2; ++ti)
#pragma unroll
        for (int r = 0; r < 4; ++r) mx[ti][r] = 0.f;

    for (int jt = 0; jt < 16; ++jt) {
        __syncthreads();
#pragma unroll
        for (int i = 0; i < 2; ++i) {
            int id = tid + i * 256;
            int r = id >> 3, qd = id & 7, lx = LX(r, qd);
            size_t g = kb + (size_t)(jt * 64 + r) * 1024 + qd * 8;
            *(float4*)&Gsh[0][lx] = *(const float4*)&Gh[g];
            *(float4*)&Gsh[1][lx] = *(const float4*)&Gl[g];
        }
        __syncthreads();

        f32x4 afw[2][2];
#pragma unroll
        for (int ti = 0; ti < 2; ++ti)
#pragma unroll
            for (int tj = 0; tj < 2; ++tj) {
                afw[ti][tj].x = 0.f; afw[ti][tj].y = 0.f;
                afw[ti][tj].z = 0.f; afw[ti][tj].w = 0.f;
            }
#pragma unroll
        for (int kc = 0; kc < 2; ++kc) {
            f16x8 aqh[2], aql[2], bgh[2], bgl[2];
#pragma unroll
            for (int ti = 0; ti < 2; ++ti) {
                int lx = LX(wm + ti * 16 + l15, kc * 4 + lq);
                aqh[ti] = *(const f16x8*)&Qsh[0][lx];
                aql[ti] = *(const f16x8*)&Qsh[1][lx];
            }
#pragma unroll
            for (int tj = 0; tj < 2; ++tj) {
                int lx = LX(wn + tj * 16 + l15, kc * 4 + lq);
                bgh[tj] = *(const f16x8*)&Gsh[0][lx];
                bgl[tj] = *(const f16x8*)&Gsh[1][lx];
            }
#pragma unroll
            for (int ti = 0; ti < 2; ++ti)
#pragma unroll
                for (int tj = 0; tj < 2; ++tj) {
                    f32x4 a = afw[ti][tj];
                    a = __builtin_amdgcn_mfma_f32_16x16x32_f16(aqh[ti], bgh[tj], a, 0, 0, 0);
                    a = __builtin_amdgcn_mfma_f32_16x16x32_f16(aqh[ti], bgl[tj], a, 0, 0, 0);
                    a = __builtin_amdgcn_mfma_f32_16x16x32_f16(aql[ti], bgh[tj], a, 0, 0, 0);
                    afw[ti][tj] = a;
                }
        }
#pragma unroll
        for (int ti = 0; ti < 2; ++ti)
#pragma unroll
            for (int tj = 0; tj < 2; ++tj)
#pragma unroll
                for (int r = 0; r < 4; ++r)
                    mx[ti][r] = fmaxf(mx[ti][r], fminf(fabsf(afw[ti][tj][r] * SCALE), 1.f));
    }
#pragma unroll
    for (int ti = 0; ti < 2; ++ti)
#pragma unroll
        for (int r = 0; r < 4; ++r) {
#pragma unroll
            for (int d = 1; d < 16; d <<= 1)
                mx[ti][r] = fmaxf(mx[ti][r], __shfl_xor(mx[ti][r], d, 64));
        }
    float* rmxp = (float*)&Ksh[0][0];
    if (l15 == 0) {
#pragma unroll
        for (int ti = 0; ti < 2; ++ti)
#pragma unroll
            for (int r = 0; r < 4; ++r)
                rmxp[(w & 1) * 64 + wm + ti * 16 + lq * 4 + r] = mx[ti][r];
    }
    __syncthreads();
    float inv[2][4];
#pragma unroll
    for (int ti = 0; ti < 2; ++ti)
#pragma unroll
        for (int r = 0; r < 4; ++r) {
            int row = wm + ti * 16 + lq * 4 + r;
            float m = fmaxf(rmxp[row], rmxp[64 + row]);
            inv[ti][r] = 1.0f / (m + 1e-6f);
        }
    __syncthreads();   // before pass-2 staging clobbers Ksh

    // ---------------- pass 2: attention ----------------
    f32x4 aco[2][2];
#pragma unroll
    for (int ti = 0; ti < 2; ++ti)
#pragma unroll
        for (int tj = 0; tj < 2; ++tj) {
            aco[ti][tj].x = 0.f; aco[ti][tj].y = 0.f;
            aco[ti][tj].z = 0.f; aco[ti][tj].w = 0.f;
        }
    float dsum[2][4];
#pragma unroll
    for (int ti = 0; ti < 2; ++ti)
#pragma unroll
        for (int r = 0; r < 4; ++r) dsum[ti][r] = 0.f;

    f16* Ps = &Gsh[0][0];                       // [64][72] overlay (9216 B)
    float* dsp = (float*)(&Gsh[0][0] + 64 * 72);

    for (int jt = 0; jt < 16; ++jt) {
        __syncthreads();
#pragma unroll
        for (int i = 0; i < 2; ++i) {
            int id = tid + i * 256;
            int r = id >> 3, qd = id & 7, lx = LX(r, qd);
            size_t g = kb + (size_t)(jt * 64 + r) * 1024 + qd * 8;
            *(float4*)&Ksh[0][lx] = *(const float4*)&Kh[g];
            *(float4*)&Ksh[1][lx] = *(const float4*)&Kl[g];
            *(float4*)&Gsh[0][lx] = *(const float4*)&Gh[g];
            *(float4*)&Gsh[1][lx] = *(const float4*)&Gl[g];
        }
        __syncthreads();

        f32x4 as_[2][2], af[2][2];
#pragma unroll
        for (int ti = 0; ti < 2; ++ti)
#pragma unroll
            for (int tj = 0; tj < 2; ++tj) {
                as_[ti][tj].x = 0.f; as_[ti][tj].y = 0.f;
                as_[ti][tj].z = 0.f; as_[ti][tj].w = 0.f;
                af[ti][tj].x = 0.f; af[ti][tj].y = 0.f;
                af[ti][tj].z = 0.f; af[ti][tj].w = 0.f;
            }
#pragma unroll
        for (int kc = 0; kc < 2; ++kc) {
            f16x8 aqh[2], aql[2], bkh[2], bkl[2], bgh[2], bgl[2];
#pragma unroll
            for (int ti = 0; ti < 2; ++ti) {
                int lx = LX(wm + ti * 16 + l15, kc * 4 + lq);
                aqh[ti] = *(const f16x8*)&Qsh[0][lx];
                aql[ti] = *(const f16x8*)&Qsh[1][lx];
            }
#pragma unroll
            for (int tj = 0; tj < 2; ++tj) {
                int lx = LX(wn + tj * 16 + l15, kc * 4 + lq);
                bkh[tj] = *(const f16x8*)&Ksh[0][lx];
                bkl[tj] = *(const f16x8*)&Ksh[1][lx];
                bgh[tj] = *(const f16x8*)&Gsh[0][lx];
                bgl[tj] = *(const f16x8*)&Gsh[1][lx];
            }
#pragma unroll
            for (int ti = 0; ti < 2; ++ti)
#pragma unroll
                for (int tj = 0; tj < 2; ++tj) {
                    f32x4 s = as_[ti][tj];
                    s = __builtin_amdgcn_mfma_f32_16x16x32_f16(aqh[ti], bkh[tj], s, 0, 0, 0);
                    s = __builtin_amdgcn_mfma_f32_16x16x32_f16(aqh[ti], bkl[tj], s, 0, 0, 0);
                    s = __builtin_amdgcn_mfma_f32_16x16x32_f16(aql[ti], bkh[tj], s, 0, 0, 0);
                    as_[ti][tj] = s;
                    f32x4 a = af[ti][tj];
                    a = __builtin_amdgcn_mfma_f32_16x16x32_f16(aqh[ti], bgh[tj], a, 0, 0, 0);
                    a = __builtin_amdgcn_mfma_f32_16x16x32_f16(aqh[ti], bgl[tj], a, 0, 0, 0);
                    a = __builtin_amdgcn_mfma_f32_16x16x32_f16(aql[ti], bgh[tj], a, 0, 0, 0);
                    af[ti][tj] = a;
                }
        }

        f16 eb[2][2][4];
#pragma unroll
        for (int ti = 0; ti < 2; ++ti)
#pragma unroll
            for (int tj = 0; tj < 2; ++tj)
#pragma unroll
                for (int r = 0; r < 4; ++r) {
                    float fn = fminf(fabsf(af[ti][tj][r] * SCALE), 1.f) * inv[ti][r];
                    float pen = (fn > 0.6f) ? 0.f : -50.f;
                    f16 e = (f16)__expf(as_[ti][tj][r] * SCALE + pen);
                    eb[ti][tj][r] = e;
                    dsum[ti][r] += (float)e;
                }
        __syncthreads();

#pragma unroll
        for (int ti = 0; ti < 2; ++ti)
#pragma unroll
            for (int tj = 0; tj < 2; ++tj)
#pragma unroll
                for (int r = 0; r < 4; ++r) {
                    int qq = wm + ti * 16 + lq * 4 + r;
                    int cc = wn + tj * 16 + l15;
                    Ps[qq * 72 + cc] = eb[ti][tj][r];
                }
#pragma unroll
        for (int i = 0; i < 2; ++i) {
            int id = tid + i * 256;
            int r = id >> 3, qd = id & 7, lx = LX(r, qd);
            size_t g = (size_t)(h * 64 + r) * 2048 + b * 1024 + jt * 64 + qd * 8;
            *(float4*)&Ksh[0][lx] = *(const float4*)&Vth[g];
            *(float4*)&Ksh[1][lx] = *(const float4*)&Vtl[g];
        }
        __syncthreads();

#pragma unroll
        for (int kc = 0; kc < 2; ++kc) {
            f16x8 ap_[2], bvh[2], bvl[2];
#pragma unroll
            for (int ti = 0; ti < 2; ++ti)
                ap_[ti] = *(const f16x8*)&Ps[(wm + ti * 16 + l15) * 72 + kc * 32 + lq * 8];
#pragma unroll
            for (int tj = 0; tj < 2; ++tj) {
                int lx = LX(wn + tj * 16 + l15, kc * 4 + lq);
                bvh[tj] = *(const f16x8*)&Ksh[0][lx];
                bvl[tj] = *(const f16x8*)&Ksh[1][lx];
            }
#pragma unroll
            for (int ti = 0; ti < 2; ++ti)
#pragma unroll
                for (int tj = 0; tj < 2; ++tj) {
                    f32x4 o = aco[ti][tj];
                    o = __builtin_amdgcn_mfma_f32_16x16x32_f16(ap_[ti], bvh[tj], o, 0, 0, 0);
                    o = __builtin_amdgcn_mfma_f32_16x16x32_f16(ap_[ti], bvl[tj], o, 0, 0, 0);
                    aco[ti][tj] = o;
                }
        }
    }

#pragma unroll
    for (int ti = 0; ti < 2; ++ti)
#pragma unroll
        for (int r = 0; r < 4; ++r) {
#pragma unroll
            for (int d = 1; d < 16; d <<= 1)
                dsum[ti][r] += __shfl_xor(dsum[ti][r], d, 64);
        }
    __syncthreads();
    if (l15 == 0) {
#pragma unroll
        for (int ti = 0; ti < 2; ++ti)
#pragma unroll
            for (int r = 0; r < 4; ++r)
                dsp[(w & 1) * 64 + wm + ti * 16 + lq * 4 + r] = dsum[ti][r];
    }
    __syncthreads();
#pragma unroll
    for (int ti = 0; ti < 2; ++ti) {
#pragma unroll
        for (int r = 0; r < 4; ++r) {
            int row = wm + ti * 16 + lq * 4 + r;
            float invd = 1.0f / (dsp[row] + dsp[64 + row]);
#pragma unroll
            for (int tj = 0; tj < 2; ++tj) {
                int qq = qr0 + row;
                int dd = h * 64 + wn + tj * 16 + l15;
                float v = aco[ti][tj][r] * invd;
                f16 hh = (f16)v;
                AOh[(size_t)(b * 2048 + qq) * 1024 + dd] = hh;
                AOl[(size_t)(b * 2048 + qq) * 1024 + dd] = (f16)(v - (float)hh);
            }
        }
    }
}

// =====================================================================
// Orchestration
// =====================================================================
extern "C" void kernel_launch(void* const* d_in, const int* in_sizes, int n_in,
                              void* d_out, int out_size, void* d_ws, size_t ws_size,
                              hipStream_t stream)
{
    const float* x   = (const float*)d_in[0];
    const float* ctx = (const float*)d_in[1];
    const float* fam = (const float*)d_in[2];
    const float* Wq  = (const float*)d_in[3];
    const float* Wk  = (const float*)d_in[4];
    const float* Wv  = (const float*)d_in[5];
    const float* Wo  = (const float*)d_in[6];
    const float* bo  = (const float*)d_in[7];
    float* out = (float*)d_out;

    const size_t nX  = (size_t)4096 * 1024;
    const size_t nC  = (size_t)2048 * 768;
    const size_t nWq = (size_t)1024 * 1024;
    const size_t nWk = (size_t)1024 * 768;
    const size_t nK  = (size_t)2048 * 1024;

    char* p = (char*)d_ws;
    f16 *xh  = (f16*)p; p += nX  * 2;  f16 *xl  = (f16*)p; p += nX  * 2;
    f16 *ch  = (f16*)p; p += nC  * 2;  f16 *cl  = (f16*)p; p += nC  * 2;
    f16 *wqh = (f16*)p; p += nWq * 2;  f16 *wql = (f16*)p; p += nWq * 2;
    f16 *wkh = (f16*)p; p += nWk * 2;  f16 *wkl = (f16*)p; p += nWk * 2;
    f16 *wvh = (f16*)p; p += nWk * 2;  f16 *wvl = (f16*)p; p += nWk * 2;
    f16 *woh = (f16*)p; p += nWq * 2;  f16 *wol = (f16*)p; p += nWq * 2;
    f16 *fmh = (f16*)p; p += nWq * 2;  f16 *fml = (f16*)p; p += nWq * 2;
    f16 *qh  = (f16*)p; p += nX  * 2;  f16 *ql  = (f16*)p; p += nX  * 2;
    f16 *kh  = (f16*)p; p += nK  * 2;  f16 *kl  = (f16*)p; p += nK  * 2;
    f16 *kth = (f16*)p; p += nK  * 2;  f16 *ktl = (f16*)p; p += nK  * 2;
    f16 *vth = (f16*)p; p += nK  * 2;  f16 *vtl = (f16*)p; p += nK  * 2;
    f16 *gh  = (f16*)p; p += nK  * 2;  f16 *gl  = (f16*)p; p += nK  * 2;
    f16 *aoh = (f16*)p; p += nX  * 2;  f16 *aol = (f16*)p; p += nX  * 2;

    const float WS  = 64.0f;       // weight pre-scale (exact pow2)
    const float IWS = 1.0f / 64.0f;

    split2<<<1024, 256, 0, stream>>>(x,   xh,  xl,  1.f, nX);
    split2<<<512,  256, 0, stream>>>(ctx, ch,  cl,  1.f, nC);
    split2<<<256,  256, 0, stream>>>(Wq,  wqh, wql, WS,  nWq);
    split2<<<256,  256, 0, stream>>>(Wk,  wkh, wkl, WS,  nWk);
    split2<<<256,  256, 0, stream>>>(Wv,  wvh, wvl, WS,  nWk);
    split2<<<256,  256, 0, stream>>>(Wo,  woh, wol, WS,  nWq);
    split2<<<256,  256, 0, stream>>>(fam, fmh, fml, 1.f, nWq);

    // q = x @ Wq^T : row-major planes
    gemm16<<<dim3(8, 32), 256, 0, stream>>>(xh, xl, wqh, wql, 1024,
        nullptr, nullptr, qh, ql, nullptr, nullptr, 0, IWS, 4096, 1024, 1024);
    // k = ctx @ Wk^T : row-major planes + transposed planes (Mt=2048)
    gemm16<<<dim3(8, 16), 256, 0, stream>>>(ch, cl, wkh, wkl, 768,
        nullptr, nullptr, kh, kl, kth, ktl, 2048, IWS, 2048, 1024, 768);
    // v = ctx @ Wv^T : transposed planes only
    gemm16<<<dim3(8, 16), 256, 0, stream>>>(ch, cl, wvh, wvl, 768,
        nullptr, nullptr, nullptr, nullptr, vth, vtl, 2048, IWS, 2048, 1024, 768);

    // G_b = fam @ k_b   (B = k^T planes, batch slice, B row stride 2048)
    for (int b = 0; b < 2; ++b) {
        gemm16<<<dim3(8, 8), 256, 0, stream>>>(fmh, fml,
            kth + (size_t)b * 1024, ktl + (size_t)b * 1024, 2048,
            nullptr, nullptr,
            gh + (size_t)b * 1024 * 1024, gl + (size_t)b * 1024 * 1024,
            nullptr, nullptr, 0, 1.f, 1024, 1024, 1024);
    }

    // fused FCA attention -> fp16x2 ao planes
    attn_mfma<<<dim3(32, 32), 256, 0, stream>>>(qh, ql, kh, kl, gh, gl,
                                                vth, vtl, aoh, aol);

    // out = ao @ Wo^T + bo
    gemm16<<<dim3(8, 32), 256, 0, stream>>>(aoh, aol, woh, wol, 1024,
        out, bo, nullptr, nullptr, nullptr, nullptr, 0, IWS, 4096, 1024, 1024);
}

// Round 6
// 408.846 us; speedup vs baseline: 5.4502x; 1.4087x over previous
//
#include <hip/hip_runtime.h>
#include <hip/hip_fp16.h>
#include <math.h>

#define SCALE 0.125f   // 64^-0.5

typedef _Float16 f16;
typedef __attribute__((ext_vector_type(8))) _Float16 f16x8;
typedef __attribute__((ext_vector_type(4))) float f32x4;

#define MFMA(a, b, c) __builtin_amdgcn_mfma_f32_16x16x32_f16((a), (b), (c), 0, 0, 0)

// async global->LDS, 16B per lane; LDS dest = wave-uniform base + lane*16
__device__ __forceinline__ void gll16(const f16* g, f16* l) {
    __builtin_amdgcn_global_load_lds(
        (const __attribute__((address_space(1))) unsigned int*)(g),
        (__attribute__((address_space(3))) unsigned int*)(l),
        16, 0, 0);
}

// =====================================================================
// split2: fp32 -> 2 fp16 planes (h, l), exact pow2 pre-scale.
// =====================================================================
__global__ __launch_bounds__(256) void split2(
    const float* __restrict__ src, f16* __restrict__ h, f16* __restrict__ l,
    float scale, size_t n)
{
    size_t i4 = ((size_t)blockIdx.x * 256 + threadIdx.x) * 4;
    size_t stride = (size_t)gridDim.x * 256 * 4;
    for (; i4 < n; i4 += stride) {
        float4 a = *(const float4*)&src[i4];
        float av[4] = {a.x * scale, a.y * scale, a.z * scale, a.w * scale};
        f16 hv[4], lv[4];
#pragma unroll
        for (int j = 0; j < 4; ++j) {
            hv[j] = (f16)av[j];
            lv[j] = (f16)(av[j] - (float)hv[j]);
        }
        *(float2*)&h[i4] = *(float2*)hv;
        *(float2*)&l[i4] = *(float2*)lv;
    }
}

// =====================================================================
// gemm16<BN>: C[M,N] = A[M,K] @ B[N,K]^T via fp16x2 planes, 3 products.
// Tile 128 x BN, BK=32, 256 thr = 4 waves. Staging via global_load_lds
// (16B/lane), bank swizzle applied in the SOURCE address (LDS linear).
// blockIdx.z batches (pointer strides Abat/Bbat/Cbat; Bstr = B row pitch).
// Fragment-read swizzle: granule g stored at slot g ^ (row&3).
// =====================================================================
#define GX(r, g) (((r) << 5) + ((((g) ^ ((r) & 3))) << 3))

template <int BN>
__global__ __launch_bounds__(256) void gemm16(
    const f16* __restrict__ Ah, const f16* __restrict__ Al, size_t Abat,
    const f16* __restrict__ Bh, const f16* __restrict__ Bl, int Bstr, size_t Bbat,
    float* __restrict__ Cf, const float* __restrict__ bias,
    f16* __restrict__ Ch, f16* __restrict__ Cl,
    f16* __restrict__ Cth, f16* __restrict__ Ctl, int Mt,
    size_t Cbat, float oscale, int M, int N, int K)
{
    constexpr int NI = BN / 32;          // n-subtiles per wave
    constexpr int BCH = BN / 16;         // 1KB chunks per B plane
    constexpr int NCH = 16 + 2 * BCH;    // total staging chunks

    __shared__ __align__(16) f16 Ash[2][128 * 32];
    __shared__ __align__(16) f16 Bsh[2][BN * 32];

    const int tid  = threadIdx.x;
    const int z    = blockIdx.z;
    Ah += z * Abat; Al += z * Abat;
    Bh += z * Bbat; Bl += z * Bbat;
    const int m0   = blockIdx.y * 128;
    const int n0   = blockIdx.x * BN;
    const int w    = tid >> 6;
    const int lane = tid & 63;
    const int wm   = (w >> 1) * 64;
    const int wn   = (w & 1) * (BN / 2);
    const int lq   = lane >> 4;
    const int l15  = lane & 15;

    f32x4 acc[4][NI];
#pragma unroll
    for (int mi = 0; mi < 4; ++mi)
#pragma unroll
        for (int ni = 0; ni < NI; ++ni) acc[mi][ni] = (f32x4){0.f, 0.f, 0.f, 0.f};

    for (int k0 = 0; k0 < K; k0 += 32) {
        __syncthreads();
#pragma unroll
        for (int c = 0; c < NCH / 4; ++c) {
            int chunk = c * 4 + w;
            const f16* gp; f16* lp;
            if (chunk < 16) {
                int pl = chunk >> 3, sub = chunk & 7;
                int r = sub * 16 + (lane >> 2);
                int g = (lane & 3) ^ (r & 3);
                gp = (pl ? Al : Ah) + (size_t)(m0 + r) * K + k0 + g * 8;
                lp = &Ash[pl][sub * 512];
            } else {
                int cb = chunk - 16;
                int pl = cb / BCH, sub = cb % BCH;
                int r = sub * 16 + (lane >> 2);
                int g = (lane & 3) ^ (r & 3);
                gp = (pl ? Bl : Bh) + (size_t)(n0 + r) * Bstr + k0 + g * 8;
                lp = &Bsh[pl][sub * 512];
            }
            gll16(gp, lp);
        }
        __syncthreads();

        f16x8 afh[4], afl[4];
#pragma unroll
        for (int mi = 0; mi < 4; ++mi) {
            int r = wm + mi * 16 + l15;
            afh[mi] = *(const f16x8*)&Ash[0][GX(r, lq)];
            afl[mi] = *(const f16x8*)&Ash[1][GX(r, lq)];
        }
#pragma unroll
        for (int ni = 0; ni < NI; ++ni) {
            int r = wn + ni * 16 + l15;
            f16x8 bh = *(const f16x8*)&Bsh[0][GX(r, lq)];
            f16x8 bl = *(const f16x8*)&Bsh[1][GX(r, lq)];
#pragma unroll
            for (int mi = 0; mi < 4; ++mi) {
                f32x4 a = acc[mi][ni];
                a = MFMA(afh[mi], bh, a);
                a = MFMA(afh[mi], bl, a);
                a = MFMA(afl[mi], bh, a);
                acc[mi][ni] = a;
            }
        }
    }

    if (Cf)  Cf  += z * Cbat;
    if (Ch)  { Ch += z * Cbat; Cl += z * Cbat; }
    if (Cth) { Cth += z * Cbat; Ctl += z * Cbat; }

#pragma unroll
    for (int mi = 0; mi < 4; ++mi) {
#pragma unroll
        for (int ni = 0; ni < NI; ++ni) {
            int row = m0 + wm + mi * 16 + lq * 4;
            int col = n0 + wn + ni * 16 + l15;
            float v[4];
#pragma unroll
            for (int r = 0; r < 4; ++r) v[r] = acc[mi][ni][r] * oscale;
            if (Cf) {
                float bb = bias ? bias[col] : 0.f;
#pragma unroll
                for (int r = 0; r < 4; ++r)
                    Cf[(size_t)(row + r) * N + col] = v[r] + bb;
            }
            if (Ch) {
#pragma unroll
                for (int r = 0; r < 4; ++r) {
                    f16 hh = (f16)v[r];
                    Ch[(size_t)(row + r) * N + col] = hh;
                    Cl[(size_t)(row + r) * N + col] = (f16)(v[r] - (float)hh);
                }
            }
            if (Cth) {
                union { f16 a[4]; float2 f; } uh, ul;
#pragma unroll
                for (int r = 0; r < 4; ++r) {
                    uh.a[r] = (f16)v[r];
                    ul.a[r] = (f16)(v[r] - (float)uh.a[r]);
                }
                *(float2*)&Cth[(size_t)col * Mt + row] = uh.f;
                *(float2*)&Ctl[(size_t)col * Mt + row] = ul.f;
            }
        }
    }
}

// =====================================================================
// MFMA fused FCA attention, fp16x2 planes, 128 q-rows/block.
// 4 waves; wave w owns q-rows [w*32, w*32+32) x ALL 64 c-cols ->
// rowmax & denom are pure in-wave shuffles. Q held in registers.
// Staging via global_load_lds, source-address swizzle (g ^= row&7).
// LDS: Ksh 16K (K planes, reused for V^T) + Gsh 16K + Ps 18K = 50 KB.
// =====================================================================
#define LX(r, qd) (((r) << 6) + ((((qd) ^ ((r) & 7))) << 3))

__global__ __launch_bounds__(256) void attn_mfma(
    const f16* __restrict__ Qh, const f16* __restrict__ Ql,
    const f16* __restrict__ Kh, const f16* __restrict__ Kl,
    const f16* __restrict__ Gh, const f16* __restrict__ Gl,
    const f16* __restrict__ Vth, const f16* __restrict__ Vtl,
    f16* __restrict__ AOh, f16* __restrict__ AOl)
{
    __shared__ __align__(16) f16 Ksh[2][4096];
    __shared__ __align__(16) f16 Gsh[2][4096];
    __shared__ __align__(16) f16 Ps[128 * 72];   // pad 72 -> 16B-aligned rows

    const int tid = threadIdx.x;
    const int bh = blockIdx.y;
    const int b = bh >> 4, h = bh & 15;
    const int qr0 = blockIdx.x * 128;
    const int w = tid >> 6, lane = tid & 63;
    const int lq = lane >> 4, l15 = lane & 15;
    const int wq = w * 32;

    const size_t qb = ((size_t)(b * 2048 + qr0)) * 1024 + h * 64;
    const size_t kb = ((size_t)(b * 1024)) * 1024 + h * 64;
    const size_t vb = (size_t)(h * 64) * 2048 + b * 1024;

    const int sr = lane >> 3;   // staging row-in-chunk
    const int ss = lane & 7;    // staging physical granule

    // ---- Q fragments in registers ----
    f16x8 aqh[2][2], aql[2][2];
#pragma unroll
    for (int ti = 0; ti < 2; ++ti)
#pragma unroll
        for (int kc = 0; kc < 2; ++kc) {
            size_t off = qb + (size_t)(wq + ti * 16 + l15) * 1024 + (kc * 4 + lq) * 8;
            aqh[ti][kc] = *(const f16x8*)&Qh[off];
            aql[ti][kc] = *(const f16x8*)&Ql[off];
        }

    // ---------------- pass 1: rowmax of min(|fw|,1) ----------------
    float mx[2][4] = {};
    for (int jt = 0; jt < 16; ++jt) {
        __syncthreads();
#pragma unroll
        for (int c = 0; c < 4; ++c) {
            int chunk = c * 4 + w;               // 0..15
            int pl = chunk >> 3, sub = chunk & 7;
            int r = sub * 8 + sr;
            int g = ss ^ (r & 7);
            const f16* gp = (pl ? Gl : Gh) + kb + (size_t)(jt * 64 + r) * 1024 + g * 8;
            gll16(gp, &Gsh[pl][sub * 512]);
        }
        __syncthreads();

#pragma unroll
        for (int tj = 0; tj < 4; ++tj) {
            f32x4 a0 = {0.f, 0.f, 0.f, 0.f}, a1 = {0.f, 0.f, 0.f, 0.f};
#pragma unroll
            for (int kc = 0; kc < 2; ++kc) {
                int lx = LX(tj * 16 + l15, kc * 4 + lq);
                f16x8 bgh = *(const f16x8*)&Gsh[0][lx];
                f16x8 bgl = *(const f16x8*)&Gsh[1][lx];
                a0 = MFMA(aqh[0][kc], bgh, a0);
                a0 = MFMA(aqh[0][kc], bgl, a0);
                a0 = MFMA(aql[0][kc], bgh, a0);
                a1 = MFMA(aqh[1][kc], bgh, a1);
                a1 = MFMA(aqh[1][kc], bgl, a1);
                a1 = MFMA(aql[1][kc], bgh, a1);
            }
#pragma unroll
            for (int r = 0; r < 4; ++r) {
                mx[0][r] = fmaxf(mx[0][r], fminf(fabsf(a0[r] * SCALE), 1.f));
                mx[1][r] = fmaxf(mx[1][r], fminf(fabsf(a1[r] * SCALE), 1.f));
            }
        }
    }
    float inv[2][4];
#pragma unroll
    for (int ti = 0; ti < 2; ++ti)
#pragma unroll
        for (int r = 0; r < 4; ++r) {
            float m = mx[ti][r];
#pragma unroll
            for (int d = 1; d < 16; d <<= 1)
                m = fmaxf(m, __shfl_xor(m, d, 64));
            inv[ti][r] = 1.0f / (m + 1e-6f);
        }

    // ---------------- pass 2: attention ----------------
    f32x4 aco[2][4];
#pragma unroll
    for (int ti = 0; ti < 2; ++ti)
#pragma unroll
        for (int dj = 0; dj < 4; ++dj) aco[ti][dj] = (f32x4){0.f, 0.f, 0.f, 0.f};
    float dsum[2][4] = {};

    for (int jt = 0; jt < 16; ++jt) {
        __syncthreads();
#pragma unroll
        for (int c = 0; c < 8; ++c) {
            int chunk = c * 4 + w;               // 0..31
            int buf = chunk >> 3, sub = chunk & 7;
            int r = sub * 8 + sr;
            int g = ss ^ (r & 7);
            size_t off = kb + (size_t)(jt * 64 + r) * 1024 + g * 8;
            const f16* gp; f16* lp;
            if (buf == 0)      { gp = Kh + off; lp = &Ksh[0][sub * 512]; }
            else if (buf == 1) { gp = Kl + off; lp = &Ksh[1][sub * 512]; }
            else if (buf == 2) { gp = Gh + off; lp = &Gsh[0][sub * 512]; }
            else               { gp = Gl + off; lp = &Gsh[1][sub * 512]; }
            gll16(gp, lp);
        }
        __syncthreads();

#pragma unroll
        for (int tj = 0; tj < 4; ++tj) {
            f32x4 s0 = {0.f, 0.f, 0.f, 0.f}, s1 = {0.f, 0.f, 0.f, 0.f};
            f32x4 f0 = {0.f, 0.f, 0.f, 0.f}, f1 = {0.f, 0.f, 0.f, 0.f};
#pragma unroll
            for (int kc = 0; kc < 2; ++kc) {
                int lx = LX(tj * 16 + l15, kc * 4 + lq);
                f16x8 bkh = *(const f16x8*)&Ksh[0][lx];
                f16x8 bkl = *(const f16x8*)&Ksh[1][lx];
                f16x8 bgh = *(const f16x8*)&Gsh[0][lx];
                f16x8 bgl = *(const f16x8*)&Gsh[1][lx];
                s0 = MFMA(aqh[0][kc], bkh, s0);
                s0 = MFMA(aqh[0][kc], bkl, s0);
                s0 = MFMA(aql[0][kc], bkh, s0);
                f0 = MFMA(aqh[0][kc], bgh, f0);
                f0 = MFMA(aqh[0][kc], bgl, f0);
                f0 = MFMA(aql[0][kc], bgh, f0);
                s1 = MFMA(aqh[1][kc], bkh, s1);
                s1 = MFMA(aqh[1][kc], bkl, s1);
                s1 = MFMA(aql[1][kc], bkh, s1);
                f1 = MFMA(aqh[1][kc], bgh, f1);
                f1 = MFMA(aqh[1][kc], bgl, f1);
                f1 = MFMA(aql[1][kc], bgh, f1);
            }
#pragma unroll
            for (int r = 0; r < 4; ++r) {
                float fn0 = fminf(fabsf(f0[r] * SCALE), 1.f) * inv[0][r];
                f16 e0 = (f16)__expf(s0[r] * SCALE + (fn0 > 0.6f ? 0.f : -50.f));
                Ps[(wq + lq * 4 + r) * 72 + tj * 16 + l15] = e0;
                dsum[0][r] += (float)e0;
                float fn1 = fminf(fabsf(f1[r] * SCALE), 1.f) * inv[1][r];
                f16 e1 = (f16)__expf(s1[r] * SCALE + (fn1 > 0.6f ? 0.f : -50.f));
                Ps[(wq + 16 + lq * 4 + r) * 72 + tj * 16 + l15] = e1;
                dsum[1][r] += (float)e1;
            }
        }
        __syncthreads();   // K/G frag reads done; V may overwrite Ksh
#pragma unroll
        for (int c = 0; c < 4; ++c) {
            int chunk = c * 4 + w;               // 0..15
            int pl = chunk >> 3, sub = chunk & 7;
            int r = sub * 8 + sr;
            int g = ss ^ (r & 7);
            const f16* gp = (pl ? Vtl : Vth) + vb + (size_t)r * 2048 + jt * 64 + g * 8;
            gll16(gp, &Ksh[pl][sub * 512]);
        }
        __syncthreads();   // V staged; Ps visible

        // PV: O[q][d] += P[q][c] * V[c][d]
#pragma unroll
        for (int kc = 0; kc < 2; ++kc) {
            f16x8 ap0 = *(const f16x8*)&Ps[(wq + l15) * 72 + kc * 32 + lq * 8];
            f16x8 ap1 = *(const f16x8*)&Ps[(wq + 16 + l15) * 72 + kc * 32 + lq * 8];
#pragma unroll
            for (int dj = 0; dj < 4; ++dj) {
                int lx = LX(dj * 16 + l15, kc * 4 + lq);
                f16x8 bvh = *(const f16x8*)&Ksh[0][lx];
                f16x8 bvl = *(const f16x8*)&Ksh[1][lx];
                f32x4 o0 = aco[0][dj];
                o0 = MFMA(ap0, bvh, o0);
                o0 = MFMA(ap0, bvl, o0);
                aco[0][dj] = o0;
                f32x4 o1 = aco[1][dj];
                o1 = MFMA(ap1, bvh, o1);
                o1 = MFMA(ap1, bvl, o1);
                aco[1][dj] = o1;
            }
        }
    }

    // ---- denominator (in-wave) + output ----
#pragma unroll
    for (int ti = 0; ti < 2; ++ti)
#pragma unroll
        for (int r = 0; r < 4; ++r) {
            float s = dsum[ti][r];
#pragma unroll
            for (int d = 1; d < 16; d <<= 1)
                s += __shfl_xor(s, d, 64);
            dsum[ti][r] = s;
        }
#pragma unroll
    for (int ti = 0; ti < 2; ++ti) {
#pragma unroll
        for (int r = 0; r < 4; ++r) {
            float invd = 1.0f / dsum[ti][r];
            int qq = qr0 + wq + ti * 16 + lq * 4 + r;
#pragma unroll
            for (int dj = 0; dj < 4; ++dj) {
                int dd = h * 64 + dj * 16 + l15;
                float v = aco[ti][dj][r] * invd;
                f16 hh = (f16)v;
                AOh[(size_t)(b * 2048 + qq) * 1024 + dd] = hh;
                AOl[(size_t)(b * 2048 + qq) * 1024 + dd] = (f16)(v - (float)hh);
            }
        }
    }
}

// =====================================================================
// Orchestration
// =====================================================================
extern "C" void kernel_launch(void* const* d_in, const int* in_sizes, int n_in,
                              void* d_out, int out_size, void* d_ws, size_t ws_size,
                              hipStream_t stream)
{
    const float* x   = (const float*)d_in[0];
    const float* ctx = (const float*)d_in[1];
    const float* fam = (const float*)d_in[2];
    const float* Wq  = (const float*)d_in[3];
    const float* Wk  = (const float*)d_in[4];
    const float* Wv  = (const float*)d_in[5];
    const float* Wo  = (const float*)d_in[6];
    const float* bo  = (const float*)d_in[7];
    float* out = (float*)d_out;

    const size_t nX  = (size_t)4096 * 1024;
    const size_t nC  = (size_t)2048 * 768;
    const size_t nWq = (size_t)1024 * 1024;
    const size_t nWk = (size_t)1024 * 768;
    const size_t nK  = (size_t)2048 * 1024;

    char* p = (char*)d_ws;
    f16 *xh  = (f16*)p; p += nX  * 2;  f16 *xl  = (f16*)p; p += nX  * 2;
    f16 *ch  = (f16*)p; p += nC  * 2;  f16 *cl  = (f16*)p; p += nC  * 2;
    f16 *wqh = (f16*)p; p += nWq * 2;  f16 *wql = (f16*)p; p += nWq * 2;
    f16 *wkh = (f16*)p; p += nWk * 2;  f16 *wkl = (f16*)p; p += nWk * 2;
    f16 *wvh = (f16*)p; p += nWk * 2;  f16 *wvl = (f16*)p; p += nWk * 2;
    f16 *woh = (f16*)p; p += nWq * 2;  f16 *wol = (f16*)p; p += nWq * 2;
    f16 *fmh = (f16*)p; p += nWq * 2;  f16 *fml = (f16*)p; p += nWq * 2;
    f16 *qh  = (f16*)p; p += nX  * 2;  f16 *ql  = (f16*)p; p += nX  * 2;
    f16 *kh  = (f16*)p; p += nK  * 2;  f16 *kl  = (f16*)p; p += nK  * 2;
    f16 *kth = (f16*)p; p += nK  * 2;  f16 *ktl = (f16*)p; p += nK  * 2;
    f16 *vth = (f16*)p; p += nK  * 2;  f16 *vtl = (f16*)p; p += nK  * 2;
    f16 *gh  = (f16*)p; p += nK  * 2;  f16 *gl  = (f16*)p; p += nK  * 2;
    f16 *aoh = (f16*)p; p += nX  * 2;  f16 *aol = (f16*)p; p += nX  * 2;

    const float WS  = 64.0f;       // weight pre-scale (exact pow2)
    const float IWS = 1.0f / 64.0f;

    split2<<<1024, 256, 0, stream>>>(x,   xh,  xl,  1.f, nX);
    split2<<<512,  256, 0, stream>>>(ctx, ch,  cl,  1.f, nC);
    split2<<<256,  256, 0, stream>>>(Wq,  wqh, wql, WS,  nWq);
    split2<<<256,  256, 0, stream>>>(Wk,  wkh, wkl, WS,  nWk);
    split2<<<256,  256, 0, stream>>>(Wv,  wvh, wvl, WS,  nWk);
    split2<<<256,  256, 0, stream>>>(Wo,  woh, wol, WS,  nWq);
    split2<<<256,  256, 0, stream>>>(fam, fmh, fml, 1.f, nWq);

    // q = x @ Wq^T : row-major fp16x2 planes (256 blocks)
    gemm16<128><<<dim3(8, 32, 1), 256, 0, stream>>>(xh, xl, 0, wqh, wql, 1024, 0,
        nullptr, nullptr, qh, ql, nullptr, nullptr, 0, 0, IWS, 4096, 1024, 1024);
    // k = ctx @ Wk^T : row-major + transposed planes (BN=64 -> 256 blocks)
    gemm16<64><<<dim3(16, 16, 1), 256, 0, stream>>>(ch, cl, 0, wkh, wkl, 768, 0,
        nullptr, nullptr, kh, kl, kth, ktl, 2048, 0, IWS, 2048, 1024, 768);
    // v = ctx @ Wv^T : transposed planes only
    gemm16<64><<<dim3(16, 16, 1), 256, 0, stream>>>(ch, cl, 0, wvh, wvl, 768, 0,
        nullptr, nullptr, nullptr, nullptr, vth, vtl, 2048, 0, IWS, 2048, 1024, 768);

    // G_b = fam @ k_b : batched over b via blockIdx.z (256 blocks total)
    gemm16<64><<<dim3(16, 8, 2), 256, 0, stream>>>(fmh, fml, 0, kth, ktl, 2048, 1024,
        nullptr, nullptr, gh, gl, nullptr, nullptr, 0, (size_t)1024 * 1024,
        1.f, 1024, 1024, 1024);

    // fused FCA attention -> fp16x2 ao planes (128 q-rows/block)
    attn_mfma<<<dim3(16, 32), 256, 0, stream>>>(qh, ql, kh, kl, gh, gl,
                                                vth, vtl, aoh, aol);

    // out = ao @ Wo^T + bo
    gemm16<128><<<dim3(8, 32, 1), 256, 0, stream>>>(aoh, aol, 0, woh, wol, 1024, 0,
        out, bo, nullptr, nullptr, nullptr, nullptr, 0, 0, IWS, 4096, 1024, 1024);
}

// Round 7
// 320.485 us; speedup vs baseline: 6.9529x; 1.2757x over previous
//
#include <hip/hip_runtime.h>
#include <hip/hip_fp16.h>
#include <math.h>

#define SCALE 0.125f   // 64^-0.5

typedef _Float16 f16;
typedef __attribute__((ext_vector_type(8))) _Float16 f16x8;
typedef __attribute__((ext_vector_type(4))) float f32x4;

#define MFMA(a, b, c) __builtin_amdgcn_mfma_f32_16x16x32_f16((a), (b), (c), 0, 0, 0)

// async global->LDS, 16B/lane; LDS dest = wave-uniform base + lane*16
__device__ __forceinline__ void gll16(const f16* g, f16* l) {
    __builtin_amdgcn_global_load_lds(
        (const __attribute__((address_space(1))) unsigned int*)(g),
        (__attribute__((address_space(3))) unsigned int*)(l),
        16, 0, 0);
}

// =====================================================================
// split_all: 7 fp32->fp16x2 split segments in one launch (blockIdx.y).
// =====================================================================
struct SplitSeg { const float* src; f16* h; f16* l; float scale; size_t n; };
struct SplitArgs { SplitSeg seg[7]; };

__global__ __launch_bounds__(256) void split_all(SplitArgs a)
{
    SplitSeg s = a.seg[blockIdx.y];
    size_t i4 = ((size_t)blockIdx.x * 256 + threadIdx.x) * 4;
    size_t stride = (size_t)gridDim.x * 256 * 4;
    for (; i4 < s.n; i4 += stride) {
        float4 v = *(const float4*)&s.src[i4];
        float av[4] = {v.x * s.scale, v.y * s.scale, v.z * s.scale, v.w * s.scale};
        f16 hv[4], lv[4];
#pragma unroll
        for (int j = 0; j < 4; ++j) {
            hv[j] = (f16)av[j];
            lv[j] = (f16)(av[j] - (float)hv[j]);
        }
        *(float2*)&s.h[i4] = *(float2*)hv;
        *(float2*)&s.l[i4] = *(float2*)lv;
    }
}

// =====================================================================
// gemm16<AP,BP>: C[M,N] = A @ B^T, fp16-plane decomposition,
// products = AP+BP-1 (2,2 -> hh+hl+lh; 1,1 -> hh). fp32 accumulate.
// Tile 128x64, 256 thr = 4 waves (2x2 of 64x32) -> 512-block grids at
// these shapes = 2 blocks/CU. Staging via global_load_lds (16B/lane),
// bank swizzle in the SOURCE address (LDS linear, as the DMA requires).
// Epilogue modes (wave-uniform): Cf fp32+bias | Ch(+Cl) row planes |
// Cth(+Ctl) transposed planes | n0>=Nsplit -> C2th single trans plane.
// blockIdx.z batching via Abat/Bbat/Cbat element offsets.
// =====================================================================
#define GX(r, g) (((r) << 5) + ((((g) ^ ((r) & 3))) << 3))

template <int AP, int BP>
__global__ __launch_bounds__(256) void gemm16(
    const f16* __restrict__ Ah, const f16* __restrict__ Al, size_t Abat,
    const f16* __restrict__ Bh, const f16* __restrict__ Bl, int Bstr, size_t Bbat,
    float* __restrict__ Cf, const float* __restrict__ bias,
    f16* __restrict__ Ch, f16* __restrict__ Cl, int Cpitch,
    f16* __restrict__ Cth, f16* __restrict__ Ctl, int Mt,
    int Nsplit, f16* __restrict__ C2th, int Mt2,
    size_t Cbat, float oscale, int M, int N, int K)
{
    constexpr int NCH = AP * 8 + BP * 4;
    __shared__ __align__(16) f16 Ash[AP][128 * 32];
    __shared__ __align__(16) f16 Bsh[BP][64 * 32];

    const int tid  = threadIdx.x;
    const int z    = blockIdx.z;
    Ah += z * Abat; if (AP == 2) Al += z * Abat;
    Bh += z * Bbat; if (BP == 2) Bl += z * Bbat;
    const int m0   = blockIdx.y * 128;
    const int n0   = blockIdx.x * 64;
    const int w    = tid >> 6;
    const int lane = tid & 63;
    const int wm   = (w >> 1) * 64;
    const int wn   = (w & 1) * 32;
    const int lq   = lane >> 4;
    const int l15  = lane & 15;

    f32x4 acc[4][2];
#pragma unroll
    for (int mi = 0; mi < 4; ++mi)
#pragma unroll
        for (int ni = 0; ni < 2; ++ni) acc[mi][ni] = (f32x4){0.f, 0.f, 0.f, 0.f};

    for (int k0 = 0; k0 < K; k0 += 32) {
        __syncthreads();
#pragma unroll
        for (int c = 0; c < NCH / 4; ++c) {
            int chunk = c * 4 + w;
            const f16* gp; f16* lp;
            if (chunk < AP * 8) {
                int pl = chunk >> 3, sub = chunk & 7;
                int r = sub * 16 + (lane >> 2);
                int g = (lane & 3) ^ (r & 3);
                gp = ((AP == 2 && pl) ? Al : Ah) + (size_t)(m0 + r) * K + k0 + g * 8;
                lp = &Ash[pl][sub * 512];
            } else {
                int cb = chunk - AP * 8;
                int pl = cb >> 2, sub = cb & 3;
                int r = sub * 16 + (lane >> 2);
                int g = (lane & 3) ^ (r & 3);
                gp = ((BP == 2 && pl) ? Bl : Bh) + (size_t)(n0 + r) * Bstr + k0 + g * 8;
                lp = &Bsh[pl][sub * 512];
            }
            gll16(gp, lp);
        }
        __syncthreads();

        f16x8 afh[4], afl[4];
#pragma unroll
        for (int mi = 0; mi < 4; ++mi) {
            int r = wm + mi * 16 + l15;
            afh[mi] = *(const f16x8*)&Ash[0][GX(r, lq)];
            if (AP == 2) afl[mi] = *(const f16x8*)&Ash[1][GX(r, lq)];
        }
#pragma unroll
        for (int ni = 0; ni < 2; ++ni) {
            int r = wn + ni * 16 + l15;
            f16x8 bh = *(const f16x8*)&Bsh[0][GX(r, lq)];
            f16x8 bl;
            if (BP == 2) bl = *(const f16x8*)&Bsh[1][GX(r, lq)];
#pragma unroll
            for (int mi = 0; mi < 4; ++mi) {
                f32x4 a = acc[mi][ni];
                a = MFMA(afh[mi], bh, a);
                if (BP == 2) a = MFMA(afh[mi], bl, a);
                if (AP == 2) a = MFMA(afl[mi], bh, a);
                acc[mi][ni] = a;
            }
        }
    }

    const bool vhalf = (Nsplit > 0) && (n0 >= Nsplit);
    if (Cf)  Cf  += z * Cbat;
    if (Ch)  { Ch += z * Cbat; if (Cl) Cl += z * Cbat; }

#pragma unroll
    for (int mi = 0; mi < 4; ++mi) {
#pragma unroll
        for (int ni = 0; ni < 2; ++ni) {
            int row = m0 + wm + mi * 16 + lq * 4;
            int col = n0 + wn + ni * 16 + l15;
            float v[4];
#pragma unroll
            for (int r = 0; r < 4; ++r) v[r] = acc[mi][ni][r] * oscale;
            if (Cf) {
                float bb = bias ? bias[col] : 0.f;
#pragma unroll
                for (int r = 0; r < 4; ++r)
                    Cf[(size_t)(row + r) * Cpitch + col] = v[r] + bb;
            } else if (vhalf) {
                union { f16 a[4]; float2 f; } uh;
#pragma unroll
                for (int r = 0; r < 4; ++r) uh.a[r] = (f16)v[r];
                *(float2*)&C2th[(size_t)(col - Nsplit) * Mt2 + row] = uh.f;
            } else {
                if (Ch) {
#pragma unroll
                    for (int r = 0; r < 4; ++r) {
                        f16 hh = (f16)v[r];
                        Ch[(size_t)(row + r) * Cpitch + col] = hh;
                        if (Cl) Cl[(size_t)(row + r) * Cpitch + col] = (f16)(v[r] - (float)hh);
                    }
                }
                if (Cth) {
                    union { f16 a[4]; float2 f; } uh, ul;
#pragma unroll
                    for (int r = 0; r < 4; ++r) {
                        uh.a[r] = (f16)v[r];
                        ul.a[r] = (f16)(v[r] - (float)uh.a[r]);
                    }
                    *(float2*)&Cth[(size_t)col * Mt + row] = uh.f;
                    if (Ctl) *(float2*)&Ctl[(size_t)col * Mt + row] = ul.f;
                }
            }
        }
    }
}

// =====================================================================
// MFMA fused FCA attention, tiered precision.
// fw: Q2 x G2, 3 products (threshold-critical).  sim: qh x kh, 1 product.
// PV: P(fp16) x Vh, 1 product.  Output: single fp16 plane.
// 128 q-rows/block, wave owns 32 q-rows x all 64 cols (in-wave reductions).
// Grid (bh, qtile): bh fast -> all 16 q-tiles of one (b,h) share an XCD
// (round-robin dispatch heuristic) -> K/G/V served from one L2.
// LDS: Ksh 8K (kh, reused for Vh) + Gsh 16K + Ps 18K = 42 KB.
// =====================================================================
#define LX(r, qd) (((r) << 6) + ((((qd) ^ ((r) & 7))) << 3))

__global__ __launch_bounds__(256) void attn_mfma(
    const f16* __restrict__ Qh, const f16* __restrict__ Ql,
    const f16* __restrict__ Kh,
    const f16* __restrict__ Gh, const f16* __restrict__ Gl,
    const f16* __restrict__ Vth, f16* __restrict__ AOh)
{
    __shared__ __align__(16) f16 Ksh[4096];
    __shared__ __align__(16) f16 Gsh[2][4096];
    __shared__ __align__(16) f16 Ps[128 * 72];

    const int tid = threadIdx.x;
    const int bh = blockIdx.x;            // fast dim -> XCD locality per (b,h)
    const int b = bh >> 4, h = bh & 15;
    const int qr0 = blockIdx.y * 128;
    const int w = tid >> 6, lane = tid & 63;
    const int lq = lane >> 4, l15 = lane & 15;
    const int wq = w * 32;

    const size_t qb = ((size_t)(b * 2048 + qr0)) * 1024 + h * 64;
    const size_t kb = ((size_t)(b * 1024)) * 1024 + h * 64;
    const size_t vb = (size_t)(h * 64) * 2048 + b * 1024;

    const int sr = lane >> 3;
    const int ss = lane & 7;

    // Q fragments in registers
    f16x8 aqh[2][2], aql[2][2];
#pragma unroll
    for (int ti = 0; ti < 2; ++ti)
#pragma unroll
        for (int kc = 0; kc < 2; ++kc) {
            size_t off = qb + (size_t)(wq + ti * 16 + l15) * 1024 + (kc * 4 + lq) * 8;
            aqh[ti][kc] = *(const f16x8*)&Qh[off];
            aql[ti][kc] = *(const f16x8*)&Ql[off];
        }

    // ---------------- pass 1: rowmax of min(|fw|,1) ----------------
    float mx[2][4] = {};
    for (int jt = 0; jt < 16; ++jt) {
        __syncthreads();
#pragma unroll
        for (int c = 0; c < 4; ++c) {
            int chunk = c * 4 + w;               // 0..15
            int pl = chunk >> 3, sub = chunk & 7;
            int r = sub * 8 + sr;
            int g = ss ^ (r & 7);
            const f16* gp = (pl ? Gl : Gh) + kb + (size_t)(jt * 64 + r) * 1024 + g * 8;
            gll16(gp, &Gsh[pl][sub * 512]);
        }
        __syncthreads();

#pragma unroll
        for (int tj = 0; tj < 4; ++tj) {
            f32x4 a0 = {0.f, 0.f, 0.f, 0.f}, a1 = {0.f, 0.f, 0.f, 0.f};
#pragma unroll
            for (int kc = 0; kc < 2; ++kc) {
                int lx = LX(tj * 16 + l15, kc * 4 + lq);
                f16x8 bgh = *(const f16x8*)&Gsh[0][lx];
                f16x8 bgl = *(const f16x8*)&Gsh[1][lx];
                a0 = MFMA(aqh[0][kc], bgh, a0);
                a0 = MFMA(aqh[0][kc], bgl, a0);
                a0 = MFMA(aql[0][kc], bgh, a0);
                a1 = MFMA(aqh[1][kc], bgh, a1);
                a1 = MFMA(aqh[1][kc], bgl, a1);
                a1 = MFMA(aql[1][kc], bgh, a1);
            }
#pragma unroll
            for (int r = 0; r < 4; ++r) {
                mx[0][r] = fmaxf(mx[0][r], fminf(fabsf(a0[r] * SCALE), 1.f));
                mx[1][r] = fmaxf(mx[1][r], fminf(fabsf(a1[r] * SCALE), 1.f));
            }
        }
    }
    float inv[2][4];
#pragma unroll
    for (int ti = 0; ti < 2; ++ti)
#pragma unroll
        for (int r = 0; r < 4; ++r) {
            float m = mx[ti][r];
#pragma unroll
            for (int d = 1; d < 16; d <<= 1)
                m = fmaxf(m, __shfl_xor(m, d, 64));
            inv[ti][r] = 1.0f / (m + 1e-6f);
        }

    // ---------------- pass 2: attention ----------------
    f32x4 aco[2][4];
#pragma unroll
    for (int ti = 0; ti < 2; ++ti)
#pragma unroll
        for (int dj = 0; dj < 4; ++dj) aco[ti][dj] = (f32x4){0.f, 0.f, 0.f, 0.f};
    float dsum[2][4] = {};

    for (int jt = 0; jt < 16; ++jt) {
        __syncthreads();
        // stage kh(8K) + gh,gl(16K): 24 chunks
#pragma unroll
        for (int c = 0; c < 6; ++c) {
            int chunk = c * 4 + w;               // 0..23
            int sub = chunk & 7;
            int r = sub * 8 + sr;
            int g = ss ^ (r & 7);
            size_t off = kb + (size_t)(jt * 64 + r) * 1024 + g * 8;
            const f16* gp; f16* lp;
            if (chunk < 8)       { gp = Kh + off; lp = &Ksh[sub * 512]; }
            else if (chunk < 16) { gp = Gh + off; lp = &Gsh[0][sub * 512]; }
            else                 { gp = Gl + off; lp = &Gsh[1][sub * 512]; }
            gll16(gp, lp);
        }
        __syncthreads();

#pragma unroll
        for (int tj = 0; tj < 4; ++tj) {
            f32x4 s0 = {0.f, 0.f, 0.f, 0.f}, s1 = {0.f, 0.f, 0.f, 0.f};
            f32x4 f0 = {0.f, 0.f, 0.f, 0.f}, f1 = {0.f, 0.f, 0.f, 0.f};
#pragma unroll
            for (int kc = 0; kc < 2; ++kc) {
                int lx = LX(tj * 16 + l15, kc * 4 + lq);
                f16x8 bkh = *(const f16x8*)&Ksh[lx];
                f16x8 bgh = *(const f16x8*)&Gsh[0][lx];
                f16x8 bgl = *(const f16x8*)&Gsh[1][lx];
                s0 = MFMA(aqh[0][kc], bkh, s0);
                f0 = MFMA(aqh[0][kc], bgh, f0);
                f0 = MFMA(aqh[0][kc], bgl, f0);
                f0 = MFMA(aql[0][kc], bgh, f0);
                s1 = MFMA(aqh[1][kc], bkh, s1);
                f1 = MFMA(aqh[1][kc], bgh, f1);
                f1 = MFMA(aqh[1][kc], bgl, f1);
                f1 = MFMA(aql[1][kc], bgh, f1);
            }
#pragma unroll
            for (int r = 0; r < 4; ++r) {
                float fn0 = fminf(fabsf(f0[r] * SCALE), 1.f) * inv[0][r];
                f16 e0 = (f16)__expf(s0[r] * SCALE + (fn0 > 0.6f ? 0.f : -50.f));
                Ps[(wq + lq * 4 + r) * 72 + tj * 16 + l15] = e0;
                dsum[0][r] += (float)e0;
                float fn1 = fminf(fabsf(f1[r] * SCALE), 1.f) * inv[1][r];
                f16 e1 = (f16)__expf(s1[r] * SCALE + (fn1 > 0.6f ? 0.f : -50.f));
                Ps[(wq + 16 + lq * 4 + r) * 72 + tj * 16 + l15] = e1;
                dsum[1][r] += (float)e1;
            }
        }
        __syncthreads();   // K/G frag reads done; Vh may overwrite Ksh
#pragma unroll
        for (int c = 0; c < 2; ++c) {
            int chunk = c * 4 + w;               // 0..7
            int sub = chunk & 7;
            int r = sub * 8 + sr;
            int g = ss ^ (r & 7);
            const f16* gp = Vth + vb + (size_t)r * 2048 + jt * 64 + g * 8;
            gll16(gp, &Ksh[sub * 512]);
        }
        __syncthreads();   // V staged; Ps visible

        // PV: O[q][d] += P[q][c] * V[c][d]
#pragma unroll
        for (int kc = 0; kc < 2; ++kc) {
            f16x8 ap0 = *(const f16x8*)&Ps[(wq + l15) * 72 + kc * 32 + lq * 8];
            f16x8 ap1 = *(const f16x8*)&Ps[(wq + 16 + l15) * 72 + kc * 32 + lq * 8];
#pragma unroll
            for (int dj = 0; dj < 4; ++dj) {
                int lx = LX(dj * 16 + l15, kc * 4 + lq);
                f16x8 bvh = *(const f16x8*)&Ksh[lx];
                aco[0][dj] = MFMA(ap0, bvh, aco[0][dj]);
                aco[1][dj] = MFMA(ap1, bvh, aco[1][dj]);
            }
        }
    }

    // denominator (in-wave) + single-plane fp16 output
#pragma unroll
    for (int ti = 0; ti < 2; ++ti)
#pragma unroll
        for (int r = 0; r < 4; ++r) {
            float s = dsum[ti][r];
#pragma unroll
            for (int d = 1; d < 16; d <<= 1)
                s += __shfl_xor(s, d, 64);
            dsum[ti][r] = s;
        }
#pragma unroll
    for (int ti = 0; ti < 2; ++ti) {
#pragma unroll
        for (int r = 0; r < 4; ++r) {
            float invd = 1.0f / dsum[ti][r];
            int qq = qr0 + wq + ti * 16 + lq * 4 + r;
#pragma unroll
            for (int dj = 0; dj < 4; ++dj) {
                int dd = h * 64 + dj * 16 + l15;
                AOh[(size_t)(b * 2048 + qq) * 1024 + dd] = (f16)(aco[ti][dj][r] * invd);
            }
        }
    }
}

// =====================================================================
// Orchestration
// =====================================================================
extern "C" void kernel_launch(void* const* d_in, const int* in_sizes, int n_in,
                              void* d_out, int out_size, void* d_ws, size_t ws_size,
                              hipStream_t stream)
{
    const float* x   = (const float*)d_in[0];
    const float* ctx = (const float*)d_in[1];
    const float* fam = (const float*)d_in[2];
    const float* Wq  = (const float*)d_in[3];
    const float* Wk  = (const float*)d_in[4];
    const float* Wv  = (const float*)d_in[5];
    const float* Wo  = (const float*)d_in[6];
    const float* bo  = (const float*)d_in[7];
    float* out = (float*)d_out;

    const size_t nX  = (size_t)4096 * 1024;
    const size_t nC  = (size_t)2048 * 768;
    const size_t nWq = (size_t)1024 * 1024;
    const size_t nWk = (size_t)1024 * 768;
    const size_t nF  = (size_t)1024 * 1024;
    const size_t nK  = (size_t)2048 * 1024;

    char* p = (char*)d_ws;
    f16 *xh   = (f16*)p; p += nX * 2;   f16 *xl   = (f16*)p; p += nX * 2;
    f16 *ch   = (f16*)p; p += nC * 2;   f16 *cl   = (f16*)p; p += nC * 2;
    f16 *wqh  = (f16*)p; p += nWq * 2;  f16 *wql  = (f16*)p; p += nWq * 2;
    f16 *wkvh = (f16*)p; p += nWk * 4;  f16 *wkvl = (f16*)p; p += nWk * 4;  // [Wk;Wv] concat
    f16 *woh  = (f16*)p; p += nWq * 2;  f16 *wol  = (f16*)p; p += nWq * 2;
    f16 *fmh  = (f16*)p; p += nF * 2;   f16 *fml  = (f16*)p; p += nF * 2;
    f16 *qh   = (f16*)p; p += nX * 2;   f16 *ql   = (f16*)p; p += nX * 2;
    f16 *kh   = (f16*)p; p += nK * 2;
    f16 *kth  = (f16*)p; p += nK * 2;   f16 *ktl  = (f16*)p; p += nK * 2;
    f16 *vth  = (f16*)p; p += nK * 2;
    f16 *gh   = (f16*)p; p += nK * 2;   f16 *gl   = (f16*)p; p += nK * 2;
    f16 *aoh  = (f16*)p; p += nX * 2;

    const float WS  = 64.0f;       // weight pre-scale (exact pow2)
    const float IWS = 1.0f / 64.0f;

    SplitArgs sa;
    sa.seg[0] = {x,   xh,          xl,          1.f, nX};
    sa.seg[1] = {ctx, ch,          cl,          1.f, nC};
    sa.seg[2] = {Wq,  wqh,         wql,         WS,  nWq};
    sa.seg[3] = {Wk,  wkvh,        wkvl,        WS,  nWk};
    sa.seg[4] = {Wv,  wkvh + nWk,  wkvl + nWk,  WS,  nWk};
    sa.seg[5] = {Wo,  woh,         wol,         WS,  nWq};
    sa.seg[6] = {fam, fmh,         fml,         1.f, nF};
    split_all<<<dim3(64, 7), 256, 0, stream>>>(sa);

    // q = x @ Wq^T : row-major fp16x2 planes (512 blocks, 2/CU)
    gemm16<2, 2><<<dim3(16, 32, 1), 256, 0, stream>>>(
        xh, xl, 0, wqh, wql, 1024, 0,
        nullptr, nullptr, qh, ql, 1024, nullptr, nullptr, 0,
        0, nullptr, 0, 0, IWS, 4096, 1024, 1024);

    // [k|v] = ctx @ [Wk|Wv]^T in ONE launch (N=2048, 512 blocks).
    // k-half: kh row-major + kth/ktl transposed; v-half: vth transposed.
    gemm16<2, 2><<<dim3(32, 16, 1), 256, 0, stream>>>(
        ch, cl, 0, wkvh, wkvl, 768, 0,
        nullptr, nullptr, kh, nullptr, 1024, kth, ktl, 2048,
        1024, vth, 2048, 0, IWS, 2048, 2048, 768);

    // G_b = fam @ k_b (B = transposed-k planes, batch via z)
    gemm16<2, 2><<<dim3(16, 8, 2), 256, 0, stream>>>(
        fmh, fml, 0, kth, ktl, 2048, 1024,
        nullptr, nullptr, gh, gl, 1024, nullptr, nullptr, 0,
        0, nullptr, 0, (size_t)1024 * 1024, 1.f, 1024, 1024, 1024);

    // fused FCA attention -> single fp16 ao plane
    attn_mfma<<<dim3(32, 16), 256, 0, stream>>>(qh, ql, kh, gh, gl, vth, aoh);

    // out = ao @ Wo^T + bo (single-plane 1-product GEMM)
    gemm16<1, 1><<<dim3(16, 32, 1), 256, 0, stream>>>(
        aoh, nullptr, 0, woh, nullptr, 1024, 0,
        out, bo, nullptr, nullptr, 1024, nullptr, nullptr, 0,
        0, nullptr, 0, 0, IWS, 4096, 1024, 1024);
}

// Round 8
// 286.267 us; speedup vs baseline: 7.7840x; 1.1195x over previous
//
#include <hip/hip_runtime.h>
#include <hip/hip_fp16.h>
#include <math.h>

#define SCALE 0.125f   // 64^-0.5

typedef _Float16 f16;
typedef __attribute__((ext_vector_type(8))) _Float16 f16x8;
typedef __attribute__((ext_vector_type(4))) float f32x4;

#define MFMA(a, b, c) __builtin_amdgcn_mfma_f32_16x16x32_f16((a), (b), (c), 0, 0, 0)

// 64-f16 rows (128B = 8 granules of 16B), XOR swizzle: granule g of row r
// lives at slot g ^ (r&7)  -> fragment reads are 2-way (free) banked.
#define LX(r, qd) (((r) << 6) + ((((qd) ^ ((r) & 7))) << 3))

// async global->LDS, 16B/lane; LDS dest = wave-uniform base + lane*16
__device__ __forceinline__ void gll16(const f16* g, f16* l) {
    __builtin_amdgcn_global_load_lds(
        (const __attribute__((address_space(1))) unsigned int*)(g),
        (__attribute__((address_space(3))) unsigned int*)(l),
        16, 0, 0);
}

// =====================================================================
// split_all: 7 fp32->fp16x2 split segments in one launch (blockIdx.y).
// =====================================================================
struct SplitSeg { const float* src; f16* h; f16* l; float scale; size_t n; };
struct SplitArgs { SplitSeg seg[7]; };

__global__ __launch_bounds__(256) void split_all(SplitArgs a)
{
    SplitSeg s = a.seg[blockIdx.y];
    size_t i4 = ((size_t)blockIdx.x * 256 + threadIdx.x) * 4;
    size_t stride = (size_t)gridDim.x * 256 * 4;
    for (; i4 < s.n; i4 += stride) {
        float4 v = *(const float4*)&s.src[i4];
        float av[4] = {v.x * s.scale, v.y * s.scale, v.z * s.scale, v.w * s.scale};
        f16 hv[4], lv[4];
#pragma unroll
        for (int j = 0; j < 4; ++j) {
            hv[j] = (f16)av[j];
            lv[j] = (f16)(av[j] - (float)hv[j]);
        }
        *(float2*)&s.h[i4] = *(float2*)hv;
        *(float2*)&s.l[i4] = *(float2*)lv;
    }
}

// =====================================================================
// gemm16<AP,BP>: C[M,N] = A @ B^T, fp16-plane decomposition,
// products = AP+BP-1. fp32 accumulate. Tile 128x64, BK=64 (half the
// barrier drains of BK=32), 256 thr = 4 waves (2x2 of 64x32).
// Staging via global_load_lds 16B/lane, swizzle in SOURCE address.
// Epilogue modes (wave-uniform): Cf fp32+bias | Ch(+Cl) row planes |
// Cth(+Ctl) transposed planes | n0>=Nsplit -> C2th single trans plane.
// blockIdx.z batching via Abat/Bbat/Cbat element offsets.
// =====================================================================
template <int AP, int BP>
__global__ __launch_bounds__(256) void gemm16(
    const f16* __restrict__ Ah, const f16* __restrict__ Al, size_t Abat,
    const f16* __restrict__ Bh, const f16* __restrict__ Bl, int Bstr, size_t Bbat,
    float* __restrict__ Cf, const float* __restrict__ bias,
    f16* __restrict__ Ch, f16* __restrict__ Cl, int Cpitch,
    f16* __restrict__ Cth, f16* __restrict__ Ctl, int Mt,
    int Nsplit, f16* __restrict__ C2th, int Mt2,
    size_t Cbat, float oscale, int M, int N, int K)
{
    constexpr int NCH = AP * 16 + BP * 8;      // 1KB staging chunks per k-step
    __shared__ __align__(16) f16 Ash[AP][128 * 64];
    __shared__ __align__(16) f16 Bsh[BP][64 * 64];

    const int tid  = threadIdx.x;
    const int z    = blockIdx.z;
    Ah += z * Abat; if (AP == 2) Al += z * Abat;
    Bh += z * Bbat; if (BP == 2) Bl += z * Bbat;
    const int m0   = blockIdx.y * 128;
    const int n0   = blockIdx.x * 64;
    const int w    = tid >> 6;
    const int lane = tid & 63;
    const int wm   = (w >> 1) * 64;
    const int wn   = (w & 1) * 32;
    const int lq   = lane >> 4;
    const int l15  = lane & 15;
    const int sr   = lane >> 3;                // row-in-chunk 0..7
    const int sg   = lane & 7;                 // physical granule slot

    f32x4 acc[4][2];
#pragma unroll
    for (int mi = 0; mi < 4; ++mi)
#pragma unroll
        for (int ni = 0; ni < 2; ++ni) acc[mi][ni] = (f32x4){0.f, 0.f, 0.f, 0.f};

    for (int k0 = 0; k0 < K; k0 += 64) {
        __syncthreads();
#pragma unroll
        for (int c = 0; c < NCH / 4; ++c) {
            int chunk = c * 4 + w;
            const f16* gp; f16* lp;
            if (chunk < AP * 16) {
                int pl = chunk >> 4, sub = chunk & 15;
                int r = sub * 8 + sr;
                int g = sg ^ (r & 7);
                gp = ((AP == 2 && pl) ? Al : Ah) + (size_t)(m0 + r) * K + k0 + g * 8;
                lp = &Ash[pl][sub * 512];
            } else {
                int cb = chunk - AP * 16;
                int pl = cb >> 3, sub = cb & 7;
                int r = sub * 8 + sr;
                int g = sg ^ (r & 7);
                gp = ((BP == 2 && pl) ? Bl : Bh) + (size_t)(n0 + r) * Bstr + k0 + g * 8;
                lp = &Bsh[pl][sub * 512];
            }
            gll16(gp, lp);
        }
        __syncthreads();

#pragma unroll
        for (int kc = 0; kc < 2; ++kc) {
            f16x8 afh[4], afl[4];
#pragma unroll
            for (int mi = 0; mi < 4; ++mi) {
                int r = wm + mi * 16 + l15;
                afh[mi] = *(const f16x8*)&Ash[0][LX(r, kc * 4 + lq)];
                if (AP == 2) afl[mi] = *(const f16x8*)&Ash[1][LX(r, kc * 4 + lq)];
            }
#pragma unroll
            for (int ni = 0; ni < 2; ++ni) {
                int r = wn + ni * 16 + l15;
                f16x8 bh = *(const f16x8*)&Bsh[0][LX(r, kc * 4 + lq)];
                f16x8 bl;
                if (BP == 2) bl = *(const f16x8*)&Bsh[1][LX(r, kc * 4 + lq)];
#pragma unroll
                for (int mi = 0; mi < 4; ++mi) {
                    f32x4 a = acc[mi][ni];
                    a = MFMA(afh[mi], bh, a);
                    if (BP == 2) a = MFMA(afh[mi], bl, a);
                    if (AP == 2) a = MFMA(afl[mi], bh, a);
                    acc[mi][ni] = a;
                }
            }
        }
    }

    const bool vhalf = (Nsplit > 0) && (n0 >= Nsplit);
    if (Cf)  Cf  += z * Cbat;
    if (Ch)  { Ch += z * Cbat; if (Cl) Cl += z * Cbat; }

#pragma unroll
    for (int mi = 0; mi < 4; ++mi) {
#pragma unroll
        for (int ni = 0; ni < 2; ++ni) {
            int row = m0 + wm + mi * 16 + lq * 4;
            int col = n0 + wn + ni * 16 + l15;
            float v[4];
#pragma unroll
            for (int r = 0; r < 4; ++r) v[r] = acc[mi][ni][r] * oscale;
            if (Cf) {
                float bb = bias ? bias[col] : 0.f;
#pragma unroll
                for (int r = 0; r < 4; ++r)
                    Cf[(size_t)(row + r) * Cpitch + col] = v[r] + bb;
            } else if (vhalf) {
                union { f16 a[4]; float2 f; } uh;
#pragma unroll
                for (int r = 0; r < 4; ++r) uh.a[r] = (f16)v[r];
                *(float2*)&C2th[(size_t)(col - Nsplit) * Mt2 + row] = uh.f;
            } else {
                if (Ch) {
#pragma unroll
                    for (int r = 0; r < 4; ++r) {
                        f16 hh = (f16)v[r];
                        Ch[(size_t)(row + r) * Cpitch + col] = hh;
                        if (Cl) Cl[(size_t)(row + r) * Cpitch + col] = (f16)(v[r] - (float)hh);
                    }
                }
                if (Cth) {
                    union { f16 a[4]; float2 f; } uh, ul;
#pragma unroll
                    for (int r = 0; r < 4; ++r) {
                        uh.a[r] = (f16)v[r];
                        ul.a[r] = (f16)(v[r] - (float)uh.a[r]);
                    }
                    *(float2*)&Cth[(size_t)col * Mt + row] = uh.f;
                    if (Ctl) *(float2*)&Ctl[(size_t)col * Mt + row] = ul.f;
                }
            }
        }
    }
}

// =====================================================================
// MFMA fused FCA attention, tiered precision.
// fw: Q2 x G2, 3 products (threshold-critical). sim: qh x kh. PV: P x Vh.
// Pass-1 EXACT early exit: rowmax(min(|fw|/8,1)) saturates at 1.0; reduce
// to row maxima each jt (in-wave butterfly), vote, break uniformly.
// Threshold algebra: fn>0.6 <=> |fw_raw| > 4.8*(m+1e-6)  (since 0.6*(m+eps)<1).
// exp via exp2(fma(s, SCALE*log2e, pen2)).
// =====================================================================
__global__ __launch_bounds__(256) void attn_mfma(
    const f16* __restrict__ Qh, const f16* __restrict__ Ql,
    const f16* __restrict__ Kh,
    const f16* __restrict__ Gh, const f16* __restrict__ Gl,
    const f16* __restrict__ Vth, f16* __restrict__ AOh)
{
    __shared__ __align__(16) f16 Ksh[4096];
    __shared__ __align__(16) f16 Gsh[2][4096];
    __shared__ __align__(16) f16 Ps[128 * 72];
    __shared__ int eflag[4];

    const int tid = threadIdx.x;
    const int bh = blockIdx.x;            // fast dim -> XCD locality per (b,h)
    const int b = bh >> 4, h = bh & 15;
    const int qr0 = blockIdx.y * 128;
    const int w = tid >> 6, lane = tid & 63;
    const int lq = lane >> 4, l15 = lane & 15;
    const int wq = w * 32;

    const size_t qb = ((size_t)(b * 2048 + qr0)) * 1024 + h * 64;
    const size_t kb = ((size_t)(b * 1024)) * 1024 + h * 64;
    const size_t vb = (size_t)(h * 64) * 2048 + b * 1024;

    const int sr = lane >> 3;
    const int ss = lane & 7;

    // Q fragments in registers
    f16x8 aqh[2][2], aql[2][2];
#pragma unroll
    for (int ti = 0; ti < 2; ++ti)
#pragma unroll
        for (int kc = 0; kc < 2; ++kc) {
            size_t off = qb + (size_t)(wq + ti * 16 + l15) * 1024 + (kc * 4 + lq) * 8;
            aqh[ti][kc] = *(const f16x8*)&Qh[off];
            aql[ti][kc] = *(const f16x8*)&Ql[off];
        }

    // ---------------- pass 1: rowmax of min(|fw|,1), early exit ----------------
    float mx[2][4] = {};
    for (int jt = 0; jt < 16; ++jt) {
#pragma unroll
        for (int c = 0; c < 4; ++c) {
            int chunk = c * 4 + w;               // 0..15
            int pl = chunk >> 3, sub = chunk & 7;
            int r = sub * 8 + sr;
            int g = ss ^ (r & 7);
            const f16* gp = (pl ? Gl : Gh) + kb + (size_t)(jt * 64 + r) * 1024 + g * 8;
            gll16(gp, &Gsh[pl][sub * 512]);
        }
        __syncthreads();

#pragma unroll
        for (int tj = 0; tj < 4; ++tj) {
            f32x4 a0 = {0.f, 0.f, 0.f, 0.f}, a1 = {0.f, 0.f, 0.f, 0.f};
#pragma unroll
            for (int kc = 0; kc < 2; ++kc) {
                int lx = LX(tj * 16 + l15, kc * 4 + lq);
                f16x8 bgh = *(const f16x8*)&Gsh[0][lx];
                f16x8 bgl = *(const f16x8*)&Gsh[1][lx];
                a0 = MFMA(aqh[0][kc], bgh, a0);
                a0 = MFMA(aqh[0][kc], bgl, a0);
                a0 = MFMA(aql[0][kc], bgh, a0);
                a1 = MFMA(aqh[1][kc], bgh, a1);
                a1 = MFMA(aqh[1][kc], bgl, a1);
                a1 = MFMA(aql[1][kc], bgh, a1);
            }
#pragma unroll
            for (int r = 0; r < 4; ++r) {
                mx[0][r] = fmaxf(mx[0][r], fminf(fabsf(a0[r] * SCALE), 1.f));
                mx[1][r] = fmaxf(mx[1][r], fminf(fabsf(a1[r] * SCALE), 1.f));
            }
        }
        // reduce partials to row maxima (over the 16 l15 lanes)
        bool done = true;
#pragma unroll
        for (int ti = 0; ti < 2; ++ti)
#pragma unroll
            for (int r = 0; r < 4; ++r) {
                float m = mx[ti][r];
#pragma unroll
                for (int d = 1; d < 16; d <<= 1)
                    m = fmaxf(m, __shfl_xor(m, d, 64));
                mx[ti][r] = m;
                done = done && (m >= 1.0f);
            }
        int wd = __all(done ? 1 : 0);
        if (lane == 0) eflag[w] = wd;
        __syncthreads();     // eflag visible; also protects Gsh for next stage
        if (eflag[0] && eflag[1] && eflag[2] && eflag[3]) break;
    }
    // per-row |fw_raw| threshold: |fw_raw| > 4.8*(m+1e-6)
    float T[2][4];
#pragma unroll
    for (int ti = 0; ti < 2; ++ti)
#pragma unroll
        for (int r = 0; r < 4; ++r)
            T[ti][r] = 4.8f * (mx[ti][r] + 1e-6f);

    // ---------------- pass 2: attention ----------------
    const float SL2E = 0.125f * 1.44269504088896f;
    const float PEN2 = -50.0f * 1.44269504088896f;
    f32x4 aco[2][4];
#pragma unroll
    for (int ti = 0; ti < 2; ++ti)
#pragma unroll
        for (int dj = 0; dj < 4; ++dj) aco[ti][dj] = (f32x4){0.f, 0.f, 0.f, 0.f};
    float dsum[2][4] = {};

    for (int jt = 0; jt < 16; ++jt) {
        __syncthreads();
        // stage kh(8K) + gh,gl(16K): 24 chunks
#pragma unroll
        for (int c = 0; c < 6; ++c) {
            int chunk = c * 4 + w;               // 0..23
            int sub = chunk & 7;
            int r = sub * 8 + sr;
            int g = ss ^ (r & 7);
            size_t off = kb + (size_t)(jt * 64 + r) * 1024 + g * 8;
            const f16* gp; f16* lp;
            if (chunk < 8)       { gp = Kh + off; lp = &Ksh[sub * 512]; }
            else if (chunk < 16) { gp = Gh + off; lp = &Gsh[0][sub * 512]; }
            else                 { gp = Gl + off; lp = &Gsh[1][sub * 512]; }
            gll16(gp, lp);
        }
        __syncthreads();

#pragma unroll
        for (int tj = 0; tj < 4; ++tj) {
            f32x4 s0 = {0.f, 0.f, 0.f, 0.f}, s1 = {0.f, 0.f, 0.f, 0.f};
            f32x4 f0 = {0.f, 0.f, 0.f, 0.f}, f1 = {0.f, 0.f, 0.f, 0.f};
#pragma unroll
            for (int kc = 0; kc < 2; ++kc) {
                int lx = LX(tj * 16 + l15, kc * 4 + lq);
                f16x8 bkh = *(const f16x8*)&Ksh[lx];
                f16x8 bgh = *(const f16x8*)&Gsh[0][lx];
                f16x8 bgl = *(const f16x8*)&Gsh[1][lx];
                s0 = MFMA(aqh[0][kc], bkh, s0);
                f0 = MFMA(aqh[0][kc], bgh, f0);
                f0 = MFMA(aqh[0][kc], bgl, f0);
                f0 = MFMA(aql[0][kc], bgh, f0);
                s1 = MFMA(aqh[1][kc], bkh, s1);
                f1 = MFMA(aqh[1][kc], bgh, f1);
                f1 = MFMA(aqh[1][kc], bgl, f1);
                f1 = MFMA(aql[1][kc], bgh, f1);
            }
#pragma unroll
            for (int r = 0; r < 4; ++r) {
                float p0 = (fabsf(f0[r]) > T[0][r]) ? 0.f : PEN2;
                f16 e0 = (f16)exp2f(fmaf(s0[r], SL2E, p0));
                Ps[(wq + lq * 4 + r) * 72 + tj * 16 + l15] = e0;
                dsum[0][r] += (float)e0;
                float p1 = (fabsf(f1[r]) > T[1][r]) ? 0.f : PEN2;
                f16 e1 = (f16)exp2f(fmaf(s1[r], SL2E, p1));
                Ps[(wq + 16 + lq * 4 + r) * 72 + tj * 16 + l15] = e1;
                dsum[1][r] += (float)e1;
            }
        }
        __syncthreads();   // K/G frag reads done; Vh may overwrite Ksh
#pragma unroll
        for (int c = 0; c < 2; ++c) {
            int chunk = c * 4 + w;               // 0..7
            int sub = chunk & 7;
            int r = sub * 8 + sr;
            int g = ss ^ (r & 7);
            const f16* gp = Vth + vb + (size_t)r * 2048 + jt * 64 + g * 8;
            gll16(gp, &Ksh[sub * 512]);
        }
        __syncthreads();   // V staged; Ps visible

        // PV: O[q][d] += P[q][c] * V[c][d]
#pragma unroll
        for (int kc = 0; kc < 2; ++kc) {
            f16x8 ap0 = *(const f16x8*)&Ps[(wq + l15) * 72 + kc * 32 + lq * 8];
            f16x8 ap1 = *(const f16x8*)&Ps[(wq + 16 + l15) * 72 + kc * 32 + lq * 8];
#pragma unroll
            for (int dj = 0; dj < 4; ++dj) {
                int lx = LX(dj * 16 + l15, kc * 4 + lq);
                f16x8 bvh = *(const f16x8*)&Ksh[lx];
                aco[0][dj] = MFMA(ap0, bvh, aco[0][dj]);
                aco[1][dj] = MFMA(ap1, bvh, aco[1][dj]);
            }
        }
    }

    // denominator (in-wave) + single-plane fp16 output
#pragma unroll
    for (int ti = 0; ti < 2; ++ti)
#pragma unroll
        for (int r = 0; r < 4; ++r) {
            float s = dsum[ti][r];
#pragma unroll
            for (int d = 1; d < 16; d <<= 1)
                s += __shfl_xor(s, d, 64);
            dsum[ti][r] = s;
        }
#pragma unroll
    for (int ti = 0; ti < 2; ++ti) {
#pragma unroll
        for (int r = 0; r < 4; ++r) {
            float invd = 1.0f / dsum[ti][r];
            int qq = qr0 + wq + ti * 16 + lq * 4 + r;
#pragma unroll
            for (int dj = 0; dj < 4; ++dj) {
                int dd = h * 64 + dj * 16 + l15;
                AOh[(size_t)(b * 2048 + qq) * 1024 + dd] = (f16)(aco[ti][dj][r] * invd);
            }
        }
    }
}

// =====================================================================
// Orchestration
// =====================================================================
extern "C" void kernel_launch(void* const* d_in, const int* in_sizes, int n_in,
                              void* d_out, int out_size, void* d_ws, size_t ws_size,
                              hipStream_t stream)
{
    const float* x   = (const float*)d_in[0];
    const float* ctx = (const float*)d_in[1];
    const float* fam = (const float*)d_in[2];
    const float* Wq  = (const float*)d_in[3];
    const float* Wk  = (const float*)d_in[4];
    const float* Wv  = (const float*)d_in[5];
    const float* Wo  = (const float*)d_in[6];
    const float* bo  = (const float*)d_in[7];
    float* out = (float*)d_out;

    const size_t nX  = (size_t)4096 * 1024;
    const size_t nC  = (size_t)2048 * 768;
    const size_t nWq = (size_t)1024 * 1024;
    const size_t nWk = (size_t)1024 * 768;
    const size_t nF  = (size_t)1024 * 1024;
    const size_t nK  = (size_t)2048 * 1024;

    char* p = (char*)d_ws;
    f16 *xh   = (f16*)p; p += nX * 2;   f16 *xl   = (f16*)p; p += nX * 2;
    f16 *ch   = (f16*)p; p += nC * 2;   f16 *cl   = (f16*)p; p += nC * 2;
    f16 *wqh  = (f16*)p; p += nWq * 2;  f16 *wql  = (f16*)p; p += nWq * 2;
    f16 *wkvh = (f16*)p; p += nWk * 4;  f16 *wkvl = (f16*)p; p += nWk * 4;  // [Wk;Wv]
    f16 *woh  = (f16*)p; p += nWq * 2;  f16 *wol  = (f16*)p; p += nWq * 2;
    f16 *fmh  = (f16*)p; p += nF * 2;   f16 *fml  = (f16*)p; p += nF * 2;
    f16 *qh   = (f16*)p; p += nX * 2;   f16 *ql   = (f16*)p; p += nX * 2;
    f16 *kh   = (f16*)p; p += nK * 2;
    f16 *kth  = (f16*)p; p += nK * 2;   f16 *ktl  = (f16*)p; p += nK * 2;
    f16 *vth  = (f16*)p; p += nK * 2;
    f16 *gh   = (f16*)p; p += nK * 2;   f16 *gl   = (f16*)p; p += nK * 2;
    f16 *aoh  = (f16*)p; p += nX * 2;

    const float WS  = 64.0f;       // weight pre-scale (exact pow2)
    const float IWS = 1.0f / 64.0f;

    SplitArgs sa;
    sa.seg[0] = {x,   xh,          xl,          1.f, nX};
    sa.seg[1] = {ctx, ch,          cl,          1.f, nC};
    sa.seg[2] = {Wq,  wqh,         wql,         WS,  nWq};
    sa.seg[3] = {Wk,  wkvh,        wkvl,        WS,  nWk};
    sa.seg[4] = {Wv,  wkvh + nWk,  wkvl + nWk,  WS,  nWk};
    sa.seg[5] = {Wo,  woh,         wol,         WS,  nWq};
    sa.seg[6] = {fam, fmh,         fml,         1.f, nF};
    split_all<<<dim3(64, 7), 256, 0, stream>>>(sa);

    // q = x @ Wq^T : row-major fp16x2 planes (512 blocks, 2/CU)
    gemm16<2, 2><<<dim3(16, 32, 1), 256, 0, stream>>>(
        xh, xl, 0, wqh, wql, 1024, 0,
        nullptr, nullptr, qh, ql, 1024, nullptr, nullptr, 0,
        0, nullptr, 0, 0, IWS, 4096, 1024, 1024);

    // [k|v] = ctx @ [Wk|Wv]^T in one launch (N=2048, 512 blocks).
    gemm16<2, 2><<<dim3(32, 16, 1), 256, 0, stream>>>(
        ch, cl, 0, wkvh, wkvl, 768, 0,
        nullptr, nullptr, kh, nullptr, 1024, kth, ktl, 2048,
        1024, vth, 2048, 0, IWS, 2048, 2048, 768);

    // G_b = fam @ k_b (B = transposed-k planes, batch via z)
    gemm16<2, 2><<<dim3(16, 8, 2), 256, 0, stream>>>(
        fmh, fml, 0, kth, ktl, 2048, 1024,
        nullptr, nullptr, gh, gl, 1024, nullptr, nullptr, 0,
        0, nullptr, 0, (size_t)1024 * 1024, 1.f, 1024, 1024, 1024);

    // fused FCA attention -> single fp16 ao plane
    attn_mfma<<<dim3(32, 16), 256, 0, stream>>>(qh, ql, kh, gh, gl, vth, aoh);

    // out = ao @ Wo^T + bo (single-plane 1-product GEMM)
    gemm16<1, 1><<<dim3(16, 32, 1), 256, 0, stream>>>(
        aoh, nullptr, 0, woh, nullptr, 1024, 0,
        out, bo, nullptr, nullptr, 1024, nullptr, nullptr, 0,
        0, nullptr, 0, 0, IWS, 4096, 1024, 1024);
}